// Round 16
// baseline (203.899 us; speedup 1.0000x reference)
//
#include <hip/hip_runtime.h>
#include <hip/hip_bf16.h>
#include <cstdint>
#include <cstddef>

// ============================================================================
// HierarchicalTransformerBlock: B=1, S=4096 (64x64 grid), D=256, NH=8, dh=32,
// DFF=1024, local windows w = 4,8,16 (stride w/2).
// Round 16: flash max-check every 2nd iter (defer-max headroom: P <= 2^22,
// bf16-safe); k_gate fused into k_xf (one less dispatch); k_colmean 256 blocks.
// Rest unchanged from round 15.
// ============================================================================

#define DEVFN __device__ __forceinline__

constexpr int S    = 4096;
constexpr int D    = 256;
constexpr int GRID = 64;
constexpr int NH   = 8;
constexpr int DH   = 32;
constexpr int NSPLIT = 8;

typedef __attribute__((ext_vector_type(8))) short bf16x8;
typedef __attribute__((ext_vector_type(4))) float f32x4;
typedef __attribute__((ext_vector_type(16))) float f32x16;
typedef __attribute__((ext_vector_type(2))) unsigned int u32x2;

DEVFN float asf(unsigned u) { return __uint_as_float(u); }

DEVFN unsigned short f2bf(float f) {  // round-to-nearest-even bf16
  unsigned u = __float_as_uint(f);
  u += 0x7fffu + ((u >> 16) & 1u);
  return (unsigned short)(u >> 16);
}
DEVFN float bf2f(unsigned short s) { return __uint_as_float(((unsigned)s) << 16); }

DEVFN unsigned pk2(float a, float b) {  // packed HW cvt (v_cvt_pk_bf16_f32)
  __hip_bfloat162 h = __float22bfloat162_rn(make_float2(a, b));
  return *(unsigned*)&h;
}

DEVFN bf16x8 pack8(float4 a, float4 b) {
  union { unsigned w[4]; bf16x8 v; } u;
  u.w[0] = pk2(a.x, a.y); u.w[1] = pk2(a.z, a.w);
  u.w[2] = pk2(b.x, b.y); u.w[3] = pk2(b.z, b.w);
  return u.v;
}

DEVFN float ex2(float x) {  // 2^x
#if __has_builtin(__builtin_amdgcn_exp2f)
  return __builtin_amdgcn_exp2f(x);
#else
  return __expf(x * 0.6931471805599453f);
#endif
}

DEVFN float gelu_t(float u) {  // tanh-form GELU (|err| <= ~3e-3 vs exact)
  const float y = 0.7978845608028654f * (u + 0.044715f * u * u * u);
  const float e = __expf(2.f * y);
  return 0.5f * u * (2.f - 2.f / (e + 1.f));
}

// ---------------------------------------------------------------------------
// Weight pre-transpose: fp32 W[K][N] -> bf16 WT[N][K]; 32x32 tiles via LDS.
// ---------------------------------------------------------------------------
__global__ __launch_bounds__(256) void k_wt(
    const float* fw, const float* wq, const float* wk, const float* wv,
    const float* wo, const float* w1, const float* w2,
    unsigned short* fwT, unsigned short* wqT, unsigned short* wkT,
    unsigned short* wvT, unsigned short* woT, unsigned short* w1T,
    unsigned short* w2T) {
  __shared__ unsigned short tile[32][36];
  const int bid = blockIdx.x;
  const float* src; unsigned short* dst; int K, N, t;
  if (bid < 192)      { src = fw; dst = fwT; K = 768;  N = 256;  t = bid; }
  else if (bid < 256) { src = wq; dst = wqT; K = 256;  N = 256;  t = bid - 192; }
  else if (bid < 320) { src = wk; dst = wkT; K = 256;  N = 256;  t = bid - 256; }
  else if (bid < 384) { src = wv; dst = wvT; K = 256;  N = 256;  t = bid - 320; }
  else if (bid < 448) { src = wo; dst = woT; K = 256;  N = 256;  t = bid - 384; }
  else if (bid < 704) { src = w1; dst = w1T; K = 256;  N = 1024; t = bid - 448; }
  else                { src = w2; dst = w2T; K = 1024; N = 256;  t = bid - 704; }
  const int nkt = K >> 5;
  const int k0 = (t % nkt) * 32, n0 = (t / nkt) * 32;
  const int i = threadIdx.x >> 3, j4 = threadIdx.x & 7;
  const float4 v = *(const float4*)(src + (size_t)(k0 + i) * N + n0 + j4 * 4);
  *(uint2*)&tile[i][j4 * 4] = make_uint2(pk2(v.x, v.y), pk2(v.z, v.w));
  __syncthreads();
  unsigned o0 = tile[j4 * 4 + 0][i], o1 = tile[j4 * 4 + 1][i];
  unsigned o2 = tile[j4 * 4 + 2][i], o3 = tile[j4 * 4 + 3][i];
  *(uint2*)(dst + (size_t)(n0 + i) * K + k0 + j4 * 4) =
      make_uint2(o0 | (o1 << 16), o2 | (o3 << 16));
}

// ---------------------------------------------------------------------------
// MFMA GEMM: C[M][N] = Ab[M][K](bf16) @ WT[N][K]^T(bf16) + bias.
// Wave computes 64x64 (2x2 grid of 32x32 tiles, 4 independent MFMA chains,
// 1:1 load:MFMA). Grid (M/64, N/64).
// ---------------------------------------------------------------------------
template <int K, int OUTBF, int ACT>
__global__ __launch_bounds__(64) void k_gemm_m(const unsigned short* __restrict__ Ab,
                                               const unsigned short* __restrict__ WT,
                                               const float* __restrict__ bias,
                                               void* __restrict__ Cout, int N) {
  const int lane = threadIdx.x;
  const int lc = lane & 31, hi = lane >> 5;
  const int m0 = blockIdx.x * 64, n0 = blockIdx.y * 64;
  const unsigned short* ap0 = Ab + (size_t)(m0 + lc) * K + hi * 8;
  const unsigned short* ap1 = Ab + (size_t)(m0 + 32 + lc) * K + hi * 8;
  const unsigned short* bp0 = WT + (size_t)(n0 + lc) * K + hi * 8;
  const unsigned short* bp1 = WT + (size_t)(n0 + 32 + lc) * K + hi * 8;
  f32x16 acc00 = {0.f,0.f,0.f,0.f,0.f,0.f,0.f,0.f,0.f,0.f,0.f,0.f,0.f,0.f,0.f,0.f};
  f32x16 acc01 = acc00, acc10 = acc00, acc11 = acc00;
#pragma unroll 4
  for (int k0 = 0; k0 < K; k0 += 16) {
    bf16x8 a0 = *(const bf16x8*)(ap0 + k0);
    bf16x8 a1 = *(const bf16x8*)(ap1 + k0);
    bf16x8 b0 = *(const bf16x8*)(bp0 + k0);
    bf16x8 b1 = *(const bf16x8*)(bp1 + k0);
    acc00 = __builtin_amdgcn_mfma_f32_32x32x16_bf16(a0, b0, acc00, 0, 0, 0);
    acc01 = __builtin_amdgcn_mfma_f32_32x32x16_bf16(a0, b1, acc01, 0, 0, 0);
    acc10 = __builtin_amdgcn_mfma_f32_32x32x16_bf16(a1, b0, acc10, 0, 0, 0);
    acc11 = __builtin_amdgcn_mfma_f32_32x32x16_bf16(a1, b1, acc11, 0, 0, 0);
  }
  const float bv0 = bias[n0 + lc], bv1 = bias[n0 + 32 + lc];
#pragma unroll
  for (int r = 0; r < 16; ++r) {
    const int row = (r & 3) + 8 * (r >> 2) + 4 * hi;
    float v00 = acc00[r] + bv0;
    float v01 = acc01[r] + bv1;
    float v10 = acc10[r] + bv0;
    float v11 = acc11[r] + bv1;
    if (ACT == 1) { v00 = gelu_t(v00); v01 = gelu_t(v01); v10 = gelu_t(v10); v11 = gelu_t(v11); }
    if (OUTBF) {
      unsigned short* c = (unsigned short*)Cout;
      c[(size_t)(m0 + row) * N + n0 + lc]           = f2bf(v00);
      c[(size_t)(m0 + row) * N + n0 + 32 + lc]      = f2bf(v01);
      c[(size_t)(m0 + 32 + row) * N + n0 + lc]      = f2bf(v10);
      c[(size_t)(m0 + 32 + row) * N + n0 + 32 + lc] = f2bf(v11);
    } else {
      float* c = (float*)Cout;
      c[(size_t)(m0 + row) * N + n0 + lc]           = v00;
      c[(size_t)(m0 + row) * N + n0 + 32 + lc]      = v01;
      c[(size_t)(m0 + 32 + row) * N + n0 + lc]      = v10;
      c[(size_t)(m0 + 32 + row) * N + n0 + 32 + lc] = v11;
    }
  }
}

// QKV: grid (S/64, 12); sel = by>>2, n0 = (by&3)*64. Q pre-scaled by
// log2(e)/sqrt(dh). Wave computes 64x64.
__global__ __launch_bounds__(64) void k_gemm_qkv(const unsigned short* __restrict__ Ab,
                                                 const unsigned short* __restrict__ wqkvT,
                                                 const float* __restrict__ bq,
                                                 const float* __restrict__ bk,
                                                 const float* __restrict__ bv,
                                                 unsigned short* __restrict__ qb,
                                                 unsigned short* __restrict__ kb,
                                                 unsigned short* __restrict__ vb) {
  const int lane = threadIdx.x;
  const int lc = lane & 31, hi = lane >> 5;
  const int m0 = blockIdx.x * 64;
  const int sel = blockIdx.y >> 2, n0 = (blockIdx.y & 3) * 64;
  const unsigned short* WT = wqkvT + (size_t)sel * 256 * 256;
  const float* bias = sel == 0 ? bq : sel == 1 ? bk : bv;
  unsigned short* out = sel == 0 ? qb : sel == 1 ? kb : vb;
  const float oscale = sel == 0 ? 0.25505889254f : 1.f;  // (1/sqrt(32))*log2(e)
  const unsigned short* ap0 = Ab + (size_t)(m0 + lc) * 256 + hi * 8;
  const unsigned short* ap1 = Ab + (size_t)(m0 + 32 + lc) * 256 + hi * 8;
  const unsigned short* bp0 = WT + (size_t)(n0 + lc) * 256 + hi * 8;
  const unsigned short* bp1 = WT + (size_t)(n0 + 32 + lc) * 256 + hi * 8;
  f32x16 acc00 = {0.f,0.f,0.f,0.f,0.f,0.f,0.f,0.f,0.f,0.f,0.f,0.f,0.f,0.f,0.f,0.f};
  f32x16 acc01 = acc00, acc10 = acc00, acc11 = acc00;
#pragma unroll 4
  for (int k0 = 0; k0 < 256; k0 += 16) {
    bf16x8 a0 = *(const bf16x8*)(ap0 + k0);
    bf16x8 a1 = *(const bf16x8*)(ap1 + k0);
    bf16x8 b0 = *(const bf16x8*)(bp0 + k0);
    bf16x8 b1 = *(const bf16x8*)(bp1 + k0);
    acc00 = __builtin_amdgcn_mfma_f32_32x32x16_bf16(a0, b0, acc00, 0, 0, 0);
    acc01 = __builtin_amdgcn_mfma_f32_32x32x16_bf16(a0, b1, acc01, 0, 0, 0);
    acc10 = __builtin_amdgcn_mfma_f32_32x32x16_bf16(a1, b0, acc10, 0, 0, 0);
    acc11 = __builtin_amdgcn_mfma_f32_32x32x16_bf16(a1, b1, acc11, 0, 0, 0);
  }
  const float bv0 = bias[n0 + lc], bv1 = bias[n0 + 32 + lc];
#pragma unroll
  for (int r = 0; r < 16; ++r) {
    const int row = (r & 3) + 8 * (r >> 2) + 4 * hi;
    out[(size_t)(m0 + row) * 256 + n0 + lc]           = f2bf((acc00[r] + bv0) * oscale);
    out[(size_t)(m0 + row) * 256 + n0 + 32 + lc]      = f2bf((acc01[r] + bv1) * oscale);
    out[(size_t)(m0 + 32 + row) * 256 + n0 + lc]      = f2bf((acc10[r] + bv0) * oscale);
    out[(size_t)(m0 + 32 + row) * 256 + n0 + 32 + lc] = f2bf((acc11[r] + bv1) * oscale);
  }
}

// ---------------------------------------------------------------------------
// Merged local windowed attention: ONE dispatch, 564 blocks x 256 threads.
// ---------------------------------------------------------------------------
constexpr int NB4 = 241, NB8 = 225, NB16 = 98;

__global__ __launch_bounds__(256, 1) void k_local_all(const float* __restrict__ x,
                                                      float* __restrict__ p0,
                                                      float* __restrict__ p1,
                                                      float* __restrict__ p2) {
  constexpr int LDE = 264;
  __shared__ unsigned short win[256][LDE];
  __shared__ float acc[256];
  const int bid = blockIdx.x;
  const int tid = threadIdx.x;
  const int wave = tid >> 6, lane = tid & 63;

  if (bid < NB4) {
    // ---- w = 4 path: per-wave window, no cross-wave sync ----
    constexpr int nS = 31;
    const int widx = bid * 4 + wave;
    if (widx < 961) {
      const int lr = lane & 15, lg = lane >> 4;
      const int row0 = (widx / nS) * 2, col0 = (widx % nS) * 2;
      unsigned short(*w4)[LDE] = &win[wave * 16];
      float* a4 = &acc[wave * 16];
      for (int e8 = lane; e8 < 16 * 32; e8 += 64) {
        const int t = e8 >> 5, c8 = (e8 & 31) * 8;
        const float* src = x + ((size_t)((row0 + (t >> 2)) * GRID + col0 + (t & 3))) * D + c8;
        *(bf16x8*)&w4[t][c8] = pack8(*(const float4*)src, *(const float4*)(src + 4));
      }
      if (lane < 16) a4[lane] = 0.f;
      asm volatile("s_waitcnt lgkmcnt(0)" ::: "memory");

      bf16x8 af[8];
#pragma unroll
      for (int k2 = 0; k2 < 8; ++k2)
        af[k2] = *(const bf16x8*)&w4[lr][k2 * 32 + lg * 8];

      float m[4], Z[4], Zi[4];
#pragma unroll
      for (int r = 0; r < 4; ++r) { m[r] = -INFINITY; Z[r] = 0.f; }
      {
        f32x4 Ca = {0.f, 0.f, 0.f, 0.f}, Cb = {0.f, 0.f, 0.f, 0.f};
#pragma unroll
        for (int k2 = 0; k2 < 8; k2 += 2) {
          bf16x8 b0 = *(const bf16x8*)&w4[lr][k2 * 32 + lg * 8];
          bf16x8 b1 = *(const bf16x8*)&w4[lr][(k2 + 1) * 32 + lg * 8];
          Ca = __builtin_amdgcn_mfma_f32_16x16x32_bf16(af[k2], b0, Ca, 0, 0, 0);
          Cb = __builtin_amdgcn_mfma_f32_16x16x32_bf16(af[k2 + 1], b1, Cb, 0, 0, 0);
        }
#pragma unroll
        for (int r = 0; r < 4; ++r) {
          const float sv = (Ca[r] + Cb[r]) * 0.0625f;
          const float nm = fmaxf(m[r], sv);
          Z[r] = Z[r] * __expf(m[r] - nm) + __expf(sv - nm);
          m[r] = nm;
        }
      }
#pragma unroll
      for (int r = 0; r < 4; ++r) {
#pragma unroll
        for (int msk = 1; msk <= 8; msk <<= 1) {
          const float om = __shfl_xor(m[r], msk), oz = __shfl_xor(Z[r], msk);
          const float nm = fmaxf(m[r], om);
          Z[r] = Z[r] * __expf(m[r] - nm) + oz * __expf(om - nm);
          m[r] = nm;
        }
        Zi[r] = 1.f / Z[r];
      }
      {
        f32x4 Ca = {0.f, 0.f, 0.f, 0.f}, Cb = {0.f, 0.f, 0.f, 0.f};
#pragma unroll
        for (int k2 = 0; k2 < 8; k2 += 2) {
          bf16x8 b0 = *(const bf16x8*)&w4[lr][k2 * 32 + lg * 8];
          bf16x8 b1 = *(const bf16x8*)&w4[lr][(k2 + 1) * 32 + lg * 8];
          Ca = __builtin_amdgcn_mfma_f32_16x16x32_bf16(af[k2], b0, Ca, 0, 0, 0);
          Cb = __builtin_amdgcn_mfma_f32_16x16x32_bf16(af[k2 + 1], b1, Cb, 0, 0, 0);
        }
        float cs = 0.f;
#pragma unroll
        for (int r = 0; r < 4; ++r)
          cs += __expf((Ca[r] + Cb[r]) * 0.0625f - m[r]) * Zi[r];
        cs += __shfl_xor(cs, 16);
        cs += __shfl_xor(cs, 32);
        if (lg == 0) atomicAdd(&a4[lr], cs);
      }
      asm volatile("s_waitcnt lgkmcnt(0)" ::: "memory");
      for (int d = lane; d < D; d += 64) {
        float s = 0.f;
#pragma unroll
        for (int k = 0; k < 16; ++k) s += a4[k] * bf2f(w4[k][d]);
        p0[(size_t)widx * D + d] = s * (1.f / 16.f);
      }
    }
  } else if (bid < NB4 + NB8) {
    // ---- w = 8 path: one window/block ----
    constexpr int nS = 15;
    const int l = bid - NB4;
    const int lr = lane & 15, lg = lane >> 4;
    const int row0 = (l / nS) * 4, col0 = (l % nS) * 4;
    for (int e8 = tid; e8 < 64 * 32; e8 += 256) {
      const int t = e8 >> 5, c8 = (e8 & 31) * 8;
      const float* src = x + ((size_t)((row0 + (t >> 3)) * GRID + col0 + (t & 7))) * D + c8;
      *(bf16x8*)&win[t][c8] = pack8(*(const float4*)src, *(const float4*)(src + 4));
    }
    if (tid < 64) acc[tid] = 0.f;
    __syncthreads();

    bf16x8 af[8];
#pragma unroll
    for (int k2 = 0; k2 < 8; ++k2)
      af[k2] = *(const bf16x8*)&win[wave * 16 + lr][k2 * 32 + lg * 8];

    float m[4], Z[4], Zi[4];
#pragma unroll
    for (int r = 0; r < 4; ++r) { m[r] = -INFINITY; Z[r] = 0.f; }
    for (int ct = 0; ct < 4; ++ct) {
      f32x4 Ca = {0.f, 0.f, 0.f, 0.f}, Cb = {0.f, 0.f, 0.f, 0.f};
#pragma unroll
      for (int k2 = 0; k2 < 8; k2 += 2) {
        bf16x8 b0 = *(const bf16x8*)&win[ct * 16 + lr][k2 * 32 + lg * 8];
        bf16x8 b1 = *(const bf16x8*)&win[ct * 16 + lr][(k2 + 1) * 32 + lg * 8];
        Ca = __builtin_amdgcn_mfma_f32_16x16x32_bf16(af[k2], b0, Ca, 0, 0, 0);
        Cb = __builtin_amdgcn_mfma_f32_16x16x32_bf16(af[k2 + 1], b1, Cb, 0, 0, 0);
      }
#pragma unroll
      for (int r = 0; r < 4; ++r) {
        const float sv = (Ca[r] + Cb[r]) * 0.0625f;
        const float nm = fmaxf(m[r], sv);
        Z[r] = Z[r] * __expf(m[r] - nm) + __expf(sv - nm);
        m[r] = nm;
      }
    }
#pragma unroll
    for (int r = 0; r < 4; ++r) {
#pragma unroll
      for (int msk = 1; msk <= 8; msk <<= 1) {
        const float om = __shfl_xor(m[r], msk), oz = __shfl_xor(Z[r], msk);
        const float nm = fmaxf(m[r], om);
        Z[r] = Z[r] * __expf(m[r] - nm) + oz * __expf(om - nm);
        m[r] = nm;
      }
      Zi[r] = 1.f / Z[r];
    }
    for (int ct = 0; ct < 4; ++ct) {
      f32x4 Ca = {0.f, 0.f, 0.f, 0.f}, Cb = {0.f, 0.f, 0.f, 0.f};
#pragma unroll
      for (int k2 = 0; k2 < 8; k2 += 2) {
        bf16x8 b0 = *(const bf16x8*)&win[ct * 16 + lr][k2 * 32 + lg * 8];
        bf16x8 b1 = *(const bf16x8*)&win[ct * 16 + lr][(k2 + 1) * 32 + lg * 8];
        Ca = __builtin_amdgcn_mfma_f32_16x16x32_bf16(af[k2], b0, Ca, 0, 0, 0);
        Cb = __builtin_amdgcn_mfma_f32_16x16x32_bf16(af[k2 + 1], b1, Cb, 0, 0, 0);
      }
      float cs = 0.f;
#pragma unroll
      for (int r = 0; r < 4; ++r)
        cs += __expf((Ca[r] + Cb[r]) * 0.0625f - m[r]) * Zi[r];
      cs += __shfl_xor(cs, 16);
      cs += __shfl_xor(cs, 32);
      if (lg == 0) atomicAdd(&acc[ct * 16 + lr], cs);
    }
    __syncthreads();
    {
      const int d = tid;
      float s = 0.f;
#pragma unroll 8
      for (int k = 0; k < 64; ++k) s += acc[k] * bf2f(win[k][d]);
      p1[(size_t)l * D + d] = s * (1.f / 64.f);
    }
  } else {
    // ---- w = 16 path: 2 blocks/window (q-split), atomic pooled ----
    constexpr int nS = 7;
    const int zz = bid - NB4 - NB8;
    const int l = zz >> 1, z = zz & 1;
    const int lc = lane & 31, hi = lane >> 5;
    const int row0 = (l / nS) * 8, col0 = (l % nS) * 8;

    for (int e8 = tid; e8 < 256 * 32; e8 += 256) {
      const int t = e8 >> 5, c8 = (e8 & 31) * 8;
      const float* src = x + ((size_t)((row0 + (t >> 4)) * GRID + col0 + (t & 15))) * D + c8;
      *(bf16x8*)&win[t][c8] = pack8(*(const float4*)src, *(const float4*)(src + 4));
    }
    acc[tid] = 0.f;
    __syncthreads();

    const int R0 = (z * 4 + wave) * 32;
    bf16x8 af[16];
#pragma unroll
    for (int k2 = 0; k2 < 16; ++k2)
      af[k2] = *(const bf16x8*)&win[R0 + lc][k2 * 16 + hi * 8];

    float m[16], Z[16], Zi[16];
#pragma unroll
    for (int r = 0; r < 16; ++r) { m[r] = -INFINITY; Z[r] = 0.f; }

    for (int ct = 0; ct < 8; ++ct) {
      f32x16 Ca = {0.f,0.f,0.f,0.f,0.f,0.f,0.f,0.f,0.f,0.f,0.f,0.f,0.f,0.f,0.f,0.f};
      f32x16 Cb = Ca;
#pragma unroll
      for (int k2 = 0; k2 < 16; k2 += 2) {
        bf16x8 b0 = *(const bf16x8*)&win[ct * 32 + lc][k2 * 16 + hi * 8];
        bf16x8 b1 = *(const bf16x8*)&win[ct * 32 + lc][(k2 + 1) * 16 + hi * 8];
        Ca = __builtin_amdgcn_mfma_f32_32x32x16_bf16(af[k2], b0, Ca, 0, 0, 0);
        Cb = __builtin_amdgcn_mfma_f32_32x32x16_bf16(af[k2 + 1], b1, Cb, 0, 0, 0);
      }
#pragma unroll
      for (int r = 0; r < 16; ++r) {
        const float sv = (Ca[r] + Cb[r]) * 0.0625f;
        const float nm = fmaxf(m[r], sv);
        Z[r] = Z[r] * __expf(m[r] - nm) + __expf(sv - nm);
        m[r] = nm;
      }
    }
#pragma unroll
    for (int r = 0; r < 16; ++r) {
#pragma unroll
      for (int msk = 1; msk <= 16; msk <<= 1) {
        const float om = __shfl_xor(m[r], msk), oz = __shfl_xor(Z[r], msk);
        const float nm = fmaxf(m[r], om);
        Z[r] = Z[r] * __expf(m[r] - nm) + oz * __expf(om - nm);
        m[r] = nm;
      }
      Zi[r] = 1.f / Z[r];
    }

    for (int ct = 0; ct < 8; ++ct) {
      f32x16 Ca = {0.f,0.f,0.f,0.f,0.f,0.f,0.f,0.f,0.f,0.f,0.f,0.f,0.f,0.f,0.f,0.f};
      f32x16 Cb = Ca;
#pragma unroll
      for (int k2 = 0; k2 < 16; k2 += 2) {
        bf16x8 b0 = *(const bf16x8*)&win[ct * 32 + lc][k2 * 16 + hi * 8];
        bf16x8 b1 = *(const bf16x8*)&win[ct * 32 + lc][(k2 + 1) * 16 + hi * 8];
        Ca = __builtin_amdgcn_mfma_f32_32x32x16_bf16(af[k2], b0, Ca, 0, 0, 0);
        Cb = __builtin_amdgcn_mfma_f32_32x32x16_bf16(af[k2 + 1], b1, Cb, 0, 0, 0);
      }
      float cs = 0.f;
#pragma unroll
      for (int r = 0; r < 16; ++r)
        cs += __expf((Ca[r] + Cb[r]) * 0.0625f - m[r]) * Zi[r];
      cs += __shfl_xor(cs, 32);
      if (hi == 0) atomicAdd(&acc[ct * 32 + lc], cs);
    }
    __syncthreads();
    {
      const int d = tid;
      float s = 0.f;
#pragma unroll 8
      for (int k = 0; k < 256; ++k) s += acc[k] * bf2f(win[k][d]);
      atomicAdd(&p2[(size_t)l * D + d], s * (1.f / 256.f));
    }
  }
}

// ---------------------------------------------------------------------------
// Overlap-average scatter of pooled windows -> catb[t][768] (bf16)
// ---------------------------------------------------------------------------
DEVFN float gatherp(const float* __restrict__ pooled, int r, int c, int W, int s, int nS, int d) {
  int amin = max(0, (r - W + s) / s), amax = min(nS - 1, r / s);
  int bmin = max(0, (c - W + s) / s), bmax = min(nS - 1, c / s);
  float acc = 0.f;
  int cnt = 0;
  for (int a = amin; a <= amax; ++a)
    for (int b = bmin; b <= bmax; ++b) { acc += pooled[(size_t)(a * nS + b) * D + d]; ++cnt; }
  return acc / (float)cnt;
}

__global__ void k_combine(const float* __restrict__ p0, const float* __restrict__ p1,
                          const float* __restrict__ p2, unsigned short* __restrict__ catb) {
  const int t = blockIdx.x, d = threadIdx.x;
  const int r = t >> 6, c = t & 63;
  unsigned short* o = catb + (size_t)t * 768;
  o[d]       = f2bf(gatherp(p0, r, c, 4, 2, 31, d));
  o[256 + d] = f2bf(gatherp(p1, r, c, 8, 4, 15, d));
  o[512 + d] = f2bf(gatherp(p2, r, c, 16, 8, 7, d));
}

// ---------------------------------------------------------------------------
// Block-wide sum of (a, b) over 256 threads
// ---------------------------------------------------------------------------
DEVFN float2 block_sum2(float a, float b) {
  __shared__ float sb[8];
#pragma unroll
  for (int m = 32; m; m >>= 1) { a += __shfl_xor(a, m); b += __shfl_xor(b, m); }
  const int w = threadIdx.x >> 6;
  __syncthreads();
  if ((threadIdx.x & 63) == 0) { sb[w] = a; sb[4 + w] = b; }
  __syncthreads();
  return make_float2(sb[0] + sb[1] + sb[2] + sb[3], sb[4] + sb[5] + sb[6] + sb[7]);
}

// out = LN(a (+ b)); optional bf16 dual write. In-place safe (out==a).
__global__ __launch_bounds__(256) void k_ln(float* __restrict__ out, unsigned short* __restrict__ outb,
                                            const float* __restrict__ a, const float* __restrict__ b,
                                            const float* __restrict__ g, const float* __restrict__ be) {
  const size_t i = (size_t)blockIdx.x * D + threadIdx.x;
  float v = a[i] + (b ? b[i] : 0.f);
  float2 s = block_sum2(v, v * v);
  float mean = s.x * (1.f / D);
  float var = s.y * (1.f / D) - mean * mean;
  const float r = (v - mean) * rsqrtf(var + 1e-5f) * g[threadIdx.x] + be[threadIdx.x];
  out[i] = r;
  if (outb) outb[i] = f2bf(r);
}

// xl = LN2(x + LN1(t1)); writes fp32 + bf16 (fuses the two post-fuse LNs)
__global__ __launch_bounds__(256) void k_ln_fuse(const float* __restrict__ t1,
                                                 const float* __restrict__ x,
                                                 float* __restrict__ xl,
                                                 unsigned short* __restrict__ xlb,
                                                 const float* __restrict__ fg,
                                                 const float* __restrict__ fbb,
                                                 const float* __restrict__ n1g,
                                                 const float* __restrict__ n1b) {
  const size_t i = (size_t)blockIdx.x * D + threadIdx.x;
  const float v1 = t1[i];
  float2 s1 = block_sum2(v1, v1 * v1);
  const float mean1 = s1.x * (1.f / D);
  const float var1 = s1.y * (1.f / D) - mean1 * mean1;
  const float r1 = (v1 - mean1) * rsqrtf(var1 + 1e-5f) * fg[threadIdx.x] + fbb[threadIdx.x];
  const float v2 = x[i] + r1;
  float2 s2 = block_sum2(v2, v2 * v2);
  const float mean2 = s2.x * (1.f / D);
  const float var2 = s2.y * (1.f / D) - mean2 * mean2;
  const float r2 = (v2 - mean2) * rsqrtf(var2 + 1e-5f) * n1g[threadIdx.x] + n1b[threadIdx.x];
  xl[i] = r2;
  xlb[i] = f2bf(r2);
}

// ---------------------------------------------------------------------------
// MFMA flash attention, split-KV x8: grid (S/64, NH, 8); 512 keys/block in
// eight 64-key iterations. exp2-domain softmax; K LDS ping-pong [64][32];
// V subtiled + tr-reads; defer-max (check every 2nd iter); split-l chains.
// ---------------------------------------------------------------------------
__global__ __launch_bounds__(256) void k_flash_mfma(const unsigned short* __restrict__ Qg,
                                                    const unsigned short* __restrict__ Kg,
                                                    const unsigned short* __restrict__ Vg,
                                                    unsigned short* __restrict__ po,
                                                    float* __restrict__ pml) {
  const int h = blockIdx.y, z = blockIdx.z;
  const int tid = threadIdx.x;
  const int wave = tid >> 6, lane = tid & 63;
  const int lr = lane & 15, lg = lane >> 4;
  constexpr int NT2 = 8;             // 8 iters x 64 keys = 512 keys per slice

  __shared__ unsigned short KS[2][64][32];
  __shared__ unsigned short VS[2][2048];

  const int q0 = blockIdx.x * 64 + wave * 16;
  const int kbase = z * 512;

  const bf16x8 qfrag = *(const bf16x8*)(Qg + (size_t)(q0 + lr) * D + h * DH + lg * 8);

  f32x4 o0 = {0.f, 0.f, 0.f, 0.f}, o1 = {0.f, 0.f, 0.f, 0.f};
  float mrow = -INFINITY, lrow = 0.f;

  const unsigned vsbase0 =
      (unsigned)(unsigned long long)(const void*)&VS[0][0] + (unsigned)(lg * 128 + lr * 2);

  const int key = tid >> 2, c8 = (tid & 3) * 8;
  const int vidx = (c8 >> 4) * 1024 + (key >> 2) * 64 + (key & 3) * 16 + (c8 & 15);
  const unsigned short* kp = Kg + (size_t)(kbase + key) * D + h * DH + c8;
  const unsigned short* vp = Vg + (size_t)(kbase + key) * D + h * DH + c8;
  constexpr int KSTEP = 64 * D;

  // prologue: stage tile 0 into buf 0
  {
    bf16x8 k0r = *(const bf16x8*)kp;
    bf16x8 v0r = *(const bf16x8*)vp;
    *(bf16x8*)&KS[0][key][c8] = k0r;
    *(bf16x8*)&VS[0][vidx] = v0r;
  }
  __syncthreads();

  for (int kt = 0; kt < NT2; ++kt) {
    const int cur = kt & 1;
    const int ktn = (kt + 1 < NT2) ? kt + 1 : kt;
    bf16x8 kreg = *(const bf16x8*)(kp + (size_t)ktn * KSTEP);
    bf16x8 vreg = *(const bf16x8*)(vp + (size_t)ktn * KSTEP);

    // swapped QK^T: s[k16][r] = S[q=lr][key = k16*16 + lg*4 + r] (log2 units)
    f32x4 s[4];
    __builtin_amdgcn_s_setprio(1);
#pragma unroll
    for (int k16 = 0; k16 < 4; ++k16) {
      bf16x8 ka = *(const bf16x8*)&KS[cur][k16 * 16 + lr][lg * 8];
      f32x4 zc = {0.f, 0.f, 0.f, 0.f};
      s[k16] = __builtin_amdgcn_mfma_f32_16x16x32_bf16(ka, qfrag, zc, 0, 0, 0);
    }
    __builtin_amdgcn_s_setprio(0);

    // issue V tr-reads early
    const unsigned vb = vsbase0 + (unsigned)(cur << 12);
    u32x2 tv000, tv001, tv010, tv011, tv100, tv101, tv110, tv111;
    asm volatile("ds_read_b64_tr_b16 %0, %1 offset:0"    : "=v"(tv000) : "v"(vb));
    asm volatile("ds_read_b64_tr_b16 %0, %1 offset:2048" : "=v"(tv001) : "v"(vb));
    asm volatile("ds_read_b64_tr_b16 %0, %1 offset:512"  : "=v"(tv010) : "v"(vb));
    asm volatile("ds_read_b64_tr_b16 %0, %1 offset:2560" : "=v"(tv011) : "v"(vb));
    asm volatile("ds_read_b64_tr_b16 %0, %1 offset:1024" : "=v"(tv100) : "v"(vb));
    asm volatile("ds_read_b64_tr_b16 %0, %1 offset:3072" : "=v"(tv101) : "v"(vb));
    asm volatile("ds_read_b64_tr_b16 %0, %1 offset:1536" : "=v"(tv110) : "v"(vb));
    asm volatile("ds_read_b64_tr_b16 %0, %1 offset:3584" : "=v"(tv111) : "v"(vb));

    // exp2-domain online softmax; defer-max checked every 2nd iter
    // (P bounded by 2^(growth+11) between checks — bf16/fp32 safe)
    if ((kt & 1) == 0) {
      float tm = fmaxf(fmaxf(fmaxf(s[0][0], s[0][1]), fmaxf(s[0][2], s[0][3])),
                       fmaxf(fmaxf(s[1][0], s[1][1]), fmaxf(s[1][2], s[1][3])));
      tm = fmaxf(tm, fmaxf(fmaxf(fmaxf(s[2][0], s[2][1]), fmaxf(s[2][2], s[2][3])),
                           fmaxf(fmaxf(s[3][0], s[3][1]), fmaxf(s[3][2], s[3][3]))));
      const bool skip = __all(tm - mrow <= 11.f);
      if (!skip) {
        float tmm = fmaxf(tm, __shfl_xor(tm, 16));
        tmm = fmaxf(tmm, __shfl_xor(tmm, 32));
        const float nm = fmaxf(mrow, tmm);
        const float cfac = ex2(mrow - nm);
        mrow = nm;
        lrow *= cfac;
#pragma unroll
        for (int r = 0; r < 4; ++r) {
          const float cr = __shfl(cfac, lg * 4 + r);
          o0[r] *= cr; o1[r] *= cr;
        }
      }
    }
    // 4 independent accumulation chains
    float pa = 0.f, pb = 0.f, pc = 0.f, pd = 0.f;
#pragma unroll
    for (int k16 = 0; k16 < 4; ++k16) {
      s[k16][0] = ex2(s[k16][0] - mrow); pa += s[k16][0];
      s[k16][1] = ex2(s[k16][1] - mrow); pb += s[k16][1];
      s[k16][2] = ex2(s[k16][2] - mrow); pc += s[k16][2];
      s[k16][3] = ex2(s[k16][3] - mrow); pd += s[k16][3];
    }
    lrow += (pa + pb) + (pc + pd);

    asm volatile("s_waitcnt lgkmcnt(0)" ::: "memory");
    __builtin_amdgcn_sched_barrier(0);

    // PV: a = lane-local P (packed via cvt_pk), b = tr-read V fragments
    union VB { u32x2 u2[2]; bf16x8 b; };
    __builtin_amdgcn_s_setprio(1);
#pragma unroll
    for (int kt2 = 0; kt2 < 2; ++kt2) {
      union { unsigned w[4]; bf16x8 v; } pu;
      pu.w[0] = pk2(s[2 * kt2][0], s[2 * kt2][1]);
      pu.w[1] = pk2(s[2 * kt2][2], s[2 * kt2][3]);
      pu.w[2] = pk2(s[2 * kt2 + 1][0], s[2 * kt2 + 1][1]);
      pu.w[3] = pk2(s[2 * kt2 + 1][2], s[2 * kt2 + 1][3]);
      VB v0f, v1f;
      if (kt2 == 0) { v0f.u2[0] = tv000; v0f.u2[1] = tv010; v1f.u2[0] = tv001; v1f.u2[1] = tv011; }
      else          { v0f.u2[0] = tv100; v0f.u2[1] = tv110; v1f.u2[0] = tv101; v1f.u2[1] = tv111; }
      o0 = __builtin_amdgcn_mfma_f32_16x16x32_bf16(pu.v, v0f.b, o0, 0, 0, 0);
      o1 = __builtin_amdgcn_mfma_f32_16x16x32_bf16(pu.v, v1f.b, o1, 0, 0, 0);
    }
    __builtin_amdgcn_s_setprio(0);

    if (kt + 1 < NT2) {
      *(bf16x8*)&KS[cur ^ 1][key][c8] = kreg;
      *(bf16x8*)&VS[cur ^ 1][vidx] = vreg;
      __syncthreads();
    }
  }

  // single cross-lane l reduction (deferred from the loop)
  lrow += __shfl_xor(lrow, 16);
  lrow += __shfl_xor(lrow, 32);

  // partial outputs (unnormalized, bf16) + per-q (m [log2], l)
#pragma unroll
  for (int r = 0; r < 4; ++r) {
    unsigned short* op = po + (size_t)z * S * D + (size_t)(q0 + lg * 4 + r) * D + h * DH + lr;
    op[0]  = f2bf(o0[r]);
    op[16] = f2bf(o1[r]);
  }
  if (lane < 16) {
    float* mlp = pml + ((size_t)(z * NH + h) * S + q0 + lr) * 2;
    mlp[0] = mrow;
    mlp[1] = lrow;
  }
}

// merge the 8 KV slices: out bf16 t1b[q][d] (m in log2 domain)
__global__ __launch_bounds__(256) void k_fmerge(const unsigned short* __restrict__ po,
                                                const float* __restrict__ pml,
                                                unsigned short* __restrict__ t1b) {
  const int t = blockIdx.x, d = threadIdx.x;
  const int h = d >> 5;
  float m[NSPLIT], l[NSPLIT];
  float M = -INFINITY;
#pragma unroll
  for (int z = 0; z < NSPLIT; ++z) {
    const float* ml = pml + ((size_t)(z * NH + h) * S + t) * 2;
    m[z] = ml[0]; l[z] = ml[1];
    M = fmaxf(M, m[z]);
  }
  float L = 0.f, acc = 0.f;
#pragma unroll
  for (int z = 0; z < NSPLIT; ++z) {
    const float a = ex2(m[z] - M);
    L += l[z] * a;
    acc += bf2f(po[(size_t)z * S * D + (size_t)t * D + d]) * a;
  }
  t1b[(size_t)t * D + d] = f2bf(acc / L);
}

// ---------------------------------------------------------------------------
// Gate helpers (gate matvec+softmax fused into k_xf)
// ---------------------------------------------------------------------------
__global__ __launch_bounds__(256) void k_colmean(const float* __restrict__ xl,
                                                 const float* __restrict__ xg,
                                                 float* __restrict__ gbuf) {
  const int j = threadIdx.x;
  const int t0 = blockIdx.x * 16;
  float s = 0.f;
  for (int t = 0; t < 16; ++t) {
    size_t i = (size_t)(t0 + t) * D + j;
    s += xl[i] + xg[i];
  }
  atomicAdd(&gbuf[j], s * 0.5f);
}

__global__ __launch_bounds__(256) void k_xf(const float* __restrict__ xl,
                                            const float* __restrict__ xg,
                                            const float* __restrict__ gbuf,
                                            const float* __restrict__ gw,
                                            const float* __restrict__ gb,
                                            float* __restrict__ xf,
                                            unsigned short* __restrict__ xfb) {
  __shared__ float ab[2];
  // per-block recompute of the 256x2 gate matvec + softmax (cheap, saves a
  // dependent dispatch)
  {
    const int j = threadIdx.x;
    const float gm = gbuf[j] * (1.f / (float)S);
    float2 s = block_sum2(gm * gw[2 * j], gm * gw[2 * j + 1]);
    if (j == 0) {
      const float g0 = s.x + gb[0], g1 = s.y + gb[1];
      const float mx = fmaxf(g0, g1);
      const float e0 = __expf(g0 - mx), e1 = __expf(g1 - mx);
      ab[0] = e0 / (e0 + e1);
      ab[1] = e1 / (e0 + e1);
    }
    __syncthreads();
  }
  const float alpha = ab[0], beta = ab[1];
  const size_t i = ((size_t)blockIdx.x * 256 + threadIdx.x) * 4;
  float4 a = *(const float4*)(xg + i);
  float4 b = *(const float4*)(xl + i);
  float4 r;
  r.x = alpha * a.x + beta * b.x;
  r.y = alpha * a.y + beta * b.y;
  r.z = alpha * a.z + beta * b.z;
  r.w = alpha * a.w + beta * b.w;
  *(float4*)(xf + i) = r;
  *(uint2*)(xfb + i) = make_uint2(pk2(r.x, r.y), pk2(r.z, r.w));
}

// ===========================================================================
extern "C" void kernel_launch(void* const* d_in, const int* in_sizes, int n_in,
                              void* d_out, int out_size, void* d_ws, size_t ws_size,
                              hipStream_t stream) {
  const float* x   = (const float*)d_in[0];
  const float* fw  = (const float*)d_in[2];
  const float* fb  = (const float*)d_in[3];
  const float* fg  = (const float*)d_in[4];
  const float* fbb = (const float*)d_in[5];
  const float* wq  = (const float*)d_in[6];
  const float* wk  = (const float*)d_in[7];
  const float* wv  = (const float*)d_in[8];
  const float* bq  = (const float*)d_in[9];
  const float* bk  = (const float*)d_in[10];
  const float* bv  = (const float*)d_in[11];
  const float* wo  = (const float*)d_in[12];
  const float* bo  = (const float*)d_in[13];
  const float* gw  = (const float*)d_in[14];
  const float* gb  = (const float*)d_in[15];
  const float* w1  = (const float*)d_in[16];
  const float* b1  = (const float*)d_in[17];
  const float* w2  = (const float*)d_in[18];
  const float* b2  = (const float*)d_in[19];
  const float* n1g = (const float*)d_in[20];
  const float* n1b = (const float*)d_in[21];
  const float* n2g = (const float*)d_in[22];
  const float* n2b = (const float*)d_in[23];
  const float* n3g = (const float*)d_in[24];
  const float* n3b = (const float*)d_in[25];
  float* out = (float*)d_out;

  // ---- workspace carve (bytes) ----
  char* base = (char*)d_ws;
  size_t off = 0;
  auto carve = [&](size_t bytes) { char* p = base + off; off += (bytes + 255) & ~(size_t)255; return p; };
  float* p0 = (float*)carve(961 * 256 * 4);
  float* p1 = (float*)carve(225 * 256 * 4);
  float* p2 = (float*)carve(49 * 256 * 4);
  unsigned short* fwT = (unsigned short*)carve(256 * 768 * 2);
  unsigned short* wqkvT = (unsigned short*)carve(3 * 256 * 256 * 2);  // q|k|v
  unsigned short* wqT = wqkvT;
  unsigned short* wkT = wqkvT + 256 * 256;
  unsigned short* wvT = wqkvT + 2 * 256 * 256;
  unsigned short* woT = (unsigned short*)carve(256 * 256 * 2);
  unsigned short* w1T = (unsigned short*)carve(1024 * 256 * 2);
  unsigned short* w2T = (unsigned short*)carve(256 * 1024 * 2);
  char* R = carve(8388608);   // catb(6.3MB) -> xg(4MB) -> hbuf(8MB)
  unsigned short* catb = (unsigned short*)R;
  float* xg            = (float*)R;
  unsigned short* hbuf = (unsigned short*)R;
  unsigned short* po = (unsigned short*)carve((size_t)NSPLIT * S * D * 2);  // 16MB
  float* pml = (float*)carve((size_t)NSPLIT * NH * S * 2 * 4);
  unsigned short* qb = (unsigned short*)carve((size_t)S * D * 2);
  unsigned short* kb = (unsigned short*)carve((size_t)S * D * 2);
  unsigned short* vb = (unsigned short*)carve((size_t)S * D * 2);
  float* xf            = (float*)qb;             // qb+kb region, dead after flash
  unsigned short* xfb  = vb;                     // vb region, dead after flash
  float* t1  = (float*)carve((size_t)S * D * 4); // fuse out; later ffo
  float* ffo = t1;
  unsigned short* t1b = (unsigned short*)carve((size_t)S * D * 2);
  float* xl  = (float*)carve((size_t)S * D * 4);
  unsigned short* xlb = (unsigned short*)carve((size_t)S * D * 2);
  float* gbuf = (float*)carve(264 * 4);

  hipMemsetAsync(gbuf, 0, 264 * sizeof(float), stream);
  hipMemsetAsync(p2, 0, 49 * 256 * sizeof(float), stream);

  // weight pre-transpose (bf16 WT[N][K]; wq/wk/wv contiguous)
  k_wt<<<dim3(960), dim3(256), 0, stream>>>(fw, wq, wk, wv, wo, w1, w2,
                                            fwT, wqT, wkT, wvT, woT, w1T, w2T);
  // local multi-scale window attention (single merged dispatch)
  k_local_all<<<dim3(NB4 + NB8 + NB16), dim3(256), 0, stream>>>(x, p0, p1, p2);
  // scatter/avg -> catb[S][768] bf16
  k_combine<<<dim3(S), dim3(256), 0, stream>>>(p0, p1, p2, catb);
  // fuse GEMM + fused LN pair
  k_gemm_m<768, 0, 0><<<dim3(S / 64, 4), dim3(64), 0, stream>>>(catb, fwT, fb, t1, 256);
  k_ln_fuse<<<dim3(S), dim3(256), 0, stream>>>(t1, x, xl, xlb, fg, fbb, n1g, n1b);
  // global MHA (bf16 q/k/v; single QKV dispatch; q pre-scaled w/ log2e)
  k_gemm_qkv<<<dim3(S / 64, 12), dim3(64), 0, stream>>>(xlb, wqkvT, bq, bk, bv, qb, kb, vb);
  k_flash_mfma<<<dim3(S / 64, NH, NSPLIT), dim3(256), 0, stream>>>(qb, kb, vb, po, pml);
  k_fmerge<<<dim3(S), dim3(256), 0, stream>>>(po, pml, t1b);
  k_gemm_m<256, 0, 0><<<dim3(S / 64, 4), dim3(64), 0, stream>>>(t1b, woT, bo, xf, 256);
  k_ln<<<dim3(S), dim3(256), 0, stream>>>(xg, nullptr, xl, xf, n2g, n2b);
  // gate (mean via atomics; matvec+softmax fused into k_xf)
  k_colmean<<<dim3(256), dim3(256), 0, stream>>>(xl, xg, gbuf);
  k_xf<<<dim3(S * D / 1024), dim3(256), 0, stream>>>(xl, xg, gbuf, gw, gb, xf, xfb);
  // FFN + final LN
  k_gemm_m<256, 1, 1><<<dim3(S / 64, 16), dim3(64), 0, stream>>>(xfb, w1T, b1, hbuf, 1024);
  k_gemm_m<1024, 0, 0><<<dim3(S / 64, 4), dim3(64), 0, stream>>>(hbuf, w2T, b2, ffo, 256);
  k_ln<<<dim3(S), dim3(256), 0, stream>>>(out, nullptr, xf, ffo, n3g, n3b);
}

// Round 17
// 202.829 us; speedup vs baseline: 1.0053x; 1.0053x over previous
//
#include <hip/hip_runtime.h>
#include <hip/hip_bf16.h>
#include <cstdint>
#include <cstddef>

// ============================================================================
// HierarchicalTransformerBlock: B=1, S=4096 (64x64 grid), D=256, NH=8, dh=32,
// DFF=1024, local windows w = 4,8,16 (stride w/2).
// Round 17: flash K-loop fully unrolled (compile-time addresses / ping-pong
// selects); p2 double-buffered (no memset, no global atomics in w16 path).
// Rest unchanged from round 16.
// ============================================================================

#define DEVFN __device__ __forceinline__

constexpr int S    = 4096;
constexpr int D    = 256;
constexpr int GRID = 64;
constexpr int NH   = 8;
constexpr int DH   = 32;
constexpr int NSPLIT = 8;

typedef __attribute__((ext_vector_type(8))) short bf16x8;
typedef __attribute__((ext_vector_type(4))) float f32x4;
typedef __attribute__((ext_vector_type(16))) float f32x16;
typedef __attribute__((ext_vector_type(2))) unsigned int u32x2;

DEVFN float asf(unsigned u) { return __uint_as_float(u); }

DEVFN unsigned short f2bf(float f) {  // round-to-nearest-even bf16
  unsigned u = __float_as_uint(f);
  u += 0x7fffu + ((u >> 16) & 1u);
  return (unsigned short)(u >> 16);
}
DEVFN float bf2f(unsigned short s) { return __uint_as_float(((unsigned)s) << 16); }

DEVFN unsigned pk2(float a, float b) {  // packed HW cvt (v_cvt_pk_bf16_f32)
  __hip_bfloat162 h = __float22bfloat162_rn(make_float2(a, b));
  return *(unsigned*)&h;
}

DEVFN bf16x8 pack8(float4 a, float4 b) {
  union { unsigned w[4]; bf16x8 v; } u;
  u.w[0] = pk2(a.x, a.y); u.w[1] = pk2(a.z, a.w);
  u.w[2] = pk2(b.x, b.y); u.w[3] = pk2(b.z, b.w);
  return u.v;
}

DEVFN float ex2(float x) {  // 2^x
#if __has_builtin(__builtin_amdgcn_exp2f)
  return __builtin_amdgcn_exp2f(x);
#else
  return __expf(x * 0.6931471805599453f);
#endif
}

DEVFN float gelu_t(float u) {  // tanh-form GELU (|err| <= ~3e-3 vs exact)
  const float y = 0.7978845608028654f * (u + 0.044715f * u * u * u);
  const float e = __expf(2.f * y);
  return 0.5f * u * (2.f - 2.f / (e + 1.f));
}

// ---------------------------------------------------------------------------
// Weight pre-transpose: fp32 W[K][N] -> bf16 WT[N][K]; 32x32 tiles via LDS.
// ---------------------------------------------------------------------------
__global__ __launch_bounds__(256) void k_wt(
    const float* fw, const float* wq, const float* wk, const float* wv,
    const float* wo, const float* w1, const float* w2,
    unsigned short* fwT, unsigned short* wqT, unsigned short* wkT,
    unsigned short* wvT, unsigned short* woT, unsigned short* w1T,
    unsigned short* w2T) {
  __shared__ unsigned short tile[32][36];
  const int bid = blockIdx.x;
  const float* src; unsigned short* dst; int K, N, t;
  if (bid < 192)      { src = fw; dst = fwT; K = 768;  N = 256;  t = bid; }
  else if (bid < 256) { src = wq; dst = wqT; K = 256;  N = 256;  t = bid - 192; }
  else if (bid < 320) { src = wk; dst = wkT; K = 256;  N = 256;  t = bid - 256; }
  else if (bid < 384) { src = wv; dst = wvT; K = 256;  N = 256;  t = bid - 320; }
  else if (bid < 448) { src = wo; dst = woT; K = 256;  N = 256;  t = bid - 384; }
  else if (bid < 704) { src = w1; dst = w1T; K = 256;  N = 1024; t = bid - 448; }
  else                { src = w2; dst = w2T; K = 1024; N = 256;  t = bid - 704; }
  const int nkt = K >> 5;
  const int k0 = (t % nkt) * 32, n0 = (t / nkt) * 32;
  const int i = threadIdx.x >> 3, j4 = threadIdx.x & 7;
  const float4 v = *(const float4*)(src + (size_t)(k0 + i) * N + n0 + j4 * 4);
  *(uint2*)&tile[i][j4 * 4] = make_uint2(pk2(v.x, v.y), pk2(v.z, v.w));
  __syncthreads();
  unsigned o0 = tile[j4 * 4 + 0][i], o1 = tile[j4 * 4 + 1][i];
  unsigned o2 = tile[j4 * 4 + 2][i], o3 = tile[j4 * 4 + 3][i];
  *(uint2*)(dst + (size_t)(n0 + i) * K + k0 + j4 * 4) =
      make_uint2(o0 | (o1 << 16), o2 | (o3 << 16));
}

// ---------------------------------------------------------------------------
// MFMA GEMM: C[M][N] = Ab[M][K](bf16) @ WT[N][K]^T(bf16) + bias.
// Wave computes 64x64 (2x2 grid of 32x32 tiles, 4 independent MFMA chains,
// 1:1 load:MFMA). Grid (M/64, N/64).
// ---------------------------------------------------------------------------
template <int K, int OUTBF, int ACT>
__global__ __launch_bounds__(64) void k_gemm_m(const unsigned short* __restrict__ Ab,
                                               const unsigned short* __restrict__ WT,
                                               const float* __restrict__ bias,
                                               void* __restrict__ Cout, int N) {
  const int lane = threadIdx.x;
  const int lc = lane & 31, hi = lane >> 5;
  const int m0 = blockIdx.x * 64, n0 = blockIdx.y * 64;
  const unsigned short* ap0 = Ab + (size_t)(m0 + lc) * K + hi * 8;
  const unsigned short* ap1 = Ab + (size_t)(m0 + 32 + lc) * K + hi * 8;
  const unsigned short* bp0 = WT + (size_t)(n0 + lc) * K + hi * 8;
  const unsigned short* bp1 = WT + (size_t)(n0 + 32 + lc) * K + hi * 8;
  f32x16 acc00 = {0.f,0.f,0.f,0.f,0.f,0.f,0.f,0.f,0.f,0.f,0.f,0.f,0.f,0.f,0.f,0.f};
  f32x16 acc01 = acc00, acc10 = acc00, acc11 = acc00;
#pragma unroll 4
  for (int k0 = 0; k0 < K; k0 += 16) {
    bf16x8 a0 = *(const bf16x8*)(ap0 + k0);
    bf16x8 a1 = *(const bf16x8*)(ap1 + k0);
    bf16x8 b0 = *(const bf16x8*)(bp0 + k0);
    bf16x8 b1 = *(const bf16x8*)(bp1 + k0);
    acc00 = __builtin_amdgcn_mfma_f32_32x32x16_bf16(a0, b0, acc00, 0, 0, 0);
    acc01 = __builtin_amdgcn_mfma_f32_32x32x16_bf16(a0, b1, acc01, 0, 0, 0);
    acc10 = __builtin_amdgcn_mfma_f32_32x32x16_bf16(a1, b0, acc10, 0, 0, 0);
    acc11 = __builtin_amdgcn_mfma_f32_32x32x16_bf16(a1, b1, acc11, 0, 0, 0);
  }
  const float bv0 = bias[n0 + lc], bv1 = bias[n0 + 32 + lc];
#pragma unroll
  for (int r = 0; r < 16; ++r) {
    const int row = (r & 3) + 8 * (r >> 2) + 4 * hi;
    float v00 = acc00[r] + bv0;
    float v01 = acc01[r] + bv1;
    float v10 = acc10[r] + bv0;
    float v11 = acc11[r] + bv1;
    if (ACT == 1) { v00 = gelu_t(v00); v01 = gelu_t(v01); v10 = gelu_t(v10); v11 = gelu_t(v11); }
    if (OUTBF) {
      unsigned short* c = (unsigned short*)Cout;
      c[(size_t)(m0 + row) * N + n0 + lc]           = f2bf(v00);
      c[(size_t)(m0 + row) * N + n0 + 32 + lc]      = f2bf(v01);
      c[(size_t)(m0 + 32 + row) * N + n0 + lc]      = f2bf(v10);
      c[(size_t)(m0 + 32 + row) * N + n0 + 32 + lc] = f2bf(v11);
    } else {
      float* c = (float*)Cout;
      c[(size_t)(m0 + row) * N + n0 + lc]           = v00;
      c[(size_t)(m0 + row) * N + n0 + 32 + lc]      = v01;
      c[(size_t)(m0 + 32 + row) * N + n0 + lc]      = v10;
      c[(size_t)(m0 + 32 + row) * N + n0 + 32 + lc] = v11;
    }
  }
}

// QKV: grid (S/64, 12); sel = by>>2, n0 = (by&3)*64. Q pre-scaled by
// log2(e)/sqrt(dh). Wave computes 64x64.
__global__ __launch_bounds__(64) void k_gemm_qkv(const unsigned short* __restrict__ Ab,
                                                 const unsigned short* __restrict__ wqkvT,
                                                 const float* __restrict__ bq,
                                                 const float* __restrict__ bk,
                                                 const float* __restrict__ bv,
                                                 unsigned short* __restrict__ qb,
                                                 unsigned short* __restrict__ kb,
                                                 unsigned short* __restrict__ vb) {
  const int lane = threadIdx.x;
  const int lc = lane & 31, hi = lane >> 5;
  const int m0 = blockIdx.x * 64;
  const int sel = blockIdx.y >> 2, n0 = (blockIdx.y & 3) * 64;
  const unsigned short* WT = wqkvT + (size_t)sel * 256 * 256;
  const float* bias = sel == 0 ? bq : sel == 1 ? bk : bv;
  unsigned short* out = sel == 0 ? qb : sel == 1 ? kb : vb;
  const float oscale = sel == 0 ? 0.25505889254f : 1.f;  // (1/sqrt(32))*log2(e)
  const unsigned short* ap0 = Ab + (size_t)(m0 + lc) * 256 + hi * 8;
  const unsigned short* ap1 = Ab + (size_t)(m0 + 32 + lc) * 256 + hi * 8;
  const unsigned short* bp0 = WT + (size_t)(n0 + lc) * 256 + hi * 8;
  const unsigned short* bp1 = WT + (size_t)(n0 + 32 + lc) * 256 + hi * 8;
  f32x16 acc00 = {0.f,0.f,0.f,0.f,0.f,0.f,0.f,0.f,0.f,0.f,0.f,0.f,0.f,0.f,0.f,0.f};
  f32x16 acc01 = acc00, acc10 = acc00, acc11 = acc00;
#pragma unroll 4
  for (int k0 = 0; k0 < 256; k0 += 16) {
    bf16x8 a0 = *(const bf16x8*)(ap0 + k0);
    bf16x8 a1 = *(const bf16x8*)(ap1 + k0);
    bf16x8 b0 = *(const bf16x8*)(bp0 + k0);
    bf16x8 b1 = *(const bf16x8*)(bp1 + k0);
    acc00 = __builtin_amdgcn_mfma_f32_32x32x16_bf16(a0, b0, acc00, 0, 0, 0);
    acc01 = __builtin_amdgcn_mfma_f32_32x32x16_bf16(a0, b1, acc01, 0, 0, 0);
    acc10 = __builtin_amdgcn_mfma_f32_32x32x16_bf16(a1, b0, acc10, 0, 0, 0);
    acc11 = __builtin_amdgcn_mfma_f32_32x32x16_bf16(a1, b1, acc11, 0, 0, 0);
  }
  const float bv0 = bias[n0 + lc], bv1 = bias[n0 + 32 + lc];
#pragma unroll
  for (int r = 0; r < 16; ++r) {
    const int row = (r & 3) + 8 * (r >> 2) + 4 * hi;
    out[(size_t)(m0 + row) * 256 + n0 + lc]           = f2bf((acc00[r] + bv0) * oscale);
    out[(size_t)(m0 + row) * 256 + n0 + 32 + lc]      = f2bf((acc01[r] + bv1) * oscale);
    out[(size_t)(m0 + 32 + row) * 256 + n0 + lc]      = f2bf((acc10[r] + bv0) * oscale);
    out[(size_t)(m0 + 32 + row) * 256 + n0 + 32 + lc] = f2bf((acc11[r] + bv1) * oscale);
  }
}

// ---------------------------------------------------------------------------
// Merged local windowed attention: ONE dispatch, 564 blocks x 256 threads.
// w16 path: z=0 writes p2a, z=1 writes p2b (both plain stores; combined later).
// ---------------------------------------------------------------------------
constexpr int NB4 = 241, NB8 = 225, NB16 = 98;

__global__ __launch_bounds__(256, 1) void k_local_all(const float* __restrict__ x,
                                                      float* __restrict__ p0,
                                                      float* __restrict__ p1,
                                                      float* __restrict__ p2a,
                                                      float* __restrict__ p2b) {
  constexpr int LDE = 264;
  __shared__ unsigned short win[256][LDE];
  __shared__ float acc[256];
  const int bid = blockIdx.x;
  const int tid = threadIdx.x;
  const int wave = tid >> 6, lane = tid & 63;

  if (bid < NB4) {
    // ---- w = 4 path: per-wave window, no cross-wave sync ----
    constexpr int nS = 31;
    const int widx = bid * 4 + wave;
    if (widx < 961) {
      const int lr = lane & 15, lg = lane >> 4;
      const int row0 = (widx / nS) * 2, col0 = (widx % nS) * 2;
      unsigned short(*w4)[LDE] = &win[wave * 16];
      float* a4 = &acc[wave * 16];
      for (int e8 = lane; e8 < 16 * 32; e8 += 64) {
        const int t = e8 >> 5, c8 = (e8 & 31) * 8;
        const float* src = x + ((size_t)((row0 + (t >> 2)) * GRID + col0 + (t & 3))) * D + c8;
        *(bf16x8*)&w4[t][c8] = pack8(*(const float4*)src, *(const float4*)(src + 4));
      }
      if (lane < 16) a4[lane] = 0.f;
      asm volatile("s_waitcnt lgkmcnt(0)" ::: "memory");

      bf16x8 af[8];
#pragma unroll
      for (int k2 = 0; k2 < 8; ++k2)
        af[k2] = *(const bf16x8*)&w4[lr][k2 * 32 + lg * 8];

      float m[4], Z[4], Zi[4];
#pragma unroll
      for (int r = 0; r < 4; ++r) { m[r] = -INFINITY; Z[r] = 0.f; }
      {
        f32x4 Ca = {0.f, 0.f, 0.f, 0.f}, Cb = {0.f, 0.f, 0.f, 0.f};
#pragma unroll
        for (int k2 = 0; k2 < 8; k2 += 2) {
          bf16x8 b0 = *(const bf16x8*)&w4[lr][k2 * 32 + lg * 8];
          bf16x8 b1 = *(const bf16x8*)&w4[lr][(k2 + 1) * 32 + lg * 8];
          Ca = __builtin_amdgcn_mfma_f32_16x16x32_bf16(af[k2], b0, Ca, 0, 0, 0);
          Cb = __builtin_amdgcn_mfma_f32_16x16x32_bf16(af[k2 + 1], b1, Cb, 0, 0, 0);
        }
#pragma unroll
        for (int r = 0; r < 4; ++r) {
          const float sv = (Ca[r] + Cb[r]) * 0.0625f;
          const float nm = fmaxf(m[r], sv);
          Z[r] = Z[r] * __expf(m[r] - nm) + __expf(sv - nm);
          m[r] = nm;
        }
      }
#pragma unroll
      for (int r = 0; r < 4; ++r) {
#pragma unroll
        for (int msk = 1; msk <= 8; msk <<= 1) {
          const float om = __shfl_xor(m[r], msk), oz = __shfl_xor(Z[r], msk);
          const float nm = fmaxf(m[r], om);
          Z[r] = Z[r] * __expf(m[r] - nm) + oz * __expf(om - nm);
          m[r] = nm;
        }
        Zi[r] = 1.f / Z[r];
      }
      {
        f32x4 Ca = {0.f, 0.f, 0.f, 0.f}, Cb = {0.f, 0.f, 0.f, 0.f};
#pragma unroll
        for (int k2 = 0; k2 < 8; k2 += 2) {
          bf16x8 b0 = *(const bf16x8*)&w4[lr][k2 * 32 + lg * 8];
          bf16x8 b1 = *(const bf16x8*)&w4[lr][(k2 + 1) * 32 + lg * 8];
          Ca = __builtin_amdgcn_mfma_f32_16x16x32_bf16(af[k2], b0, Ca, 0, 0, 0);
          Cb = __builtin_amdgcn_mfma_f32_16x16x32_bf16(af[k2 + 1], b1, Cb, 0, 0, 0);
        }
        float cs = 0.f;
#pragma unroll
        for (int r = 0; r < 4; ++r)
          cs += __expf((Ca[r] + Cb[r]) * 0.0625f - m[r]) * Zi[r];
        cs += __shfl_xor(cs, 16);
        cs += __shfl_xor(cs, 32);
        if (lg == 0) atomicAdd(&a4[lr], cs);
      }
      asm volatile("s_waitcnt lgkmcnt(0)" ::: "memory");
      for (int d = lane; d < D; d += 64) {
        float s = 0.f;
#pragma unroll
        for (int k = 0; k < 16; ++k) s += a4[k] * bf2f(w4[k][d]);
        p0[(size_t)widx * D + d] = s * (1.f / 16.f);
      }
    }
  } else if (bid < NB4 + NB8) {
    // ---- w = 8 path: one window/block ----
    constexpr int nS = 15;
    const int l = bid - NB4;
    const int lr = lane & 15, lg = lane >> 4;
    const int row0 = (l / nS) * 4, col0 = (l % nS) * 4;
    for (int e8 = tid; e8 < 64 * 32; e8 += 256) {
      const int t = e8 >> 5, c8 = (e8 & 31) * 8;
      const float* src = x + ((size_t)((row0 + (t >> 3)) * GRID + col0 + (t & 7))) * D + c8;
      *(bf16x8*)&win[t][c8] = pack8(*(const float4*)src, *(const float4*)(src + 4));
    }
    if (tid < 64) acc[tid] = 0.f;
    __syncthreads();

    bf16x8 af[8];
#pragma unroll
    for (int k2 = 0; k2 < 8; ++k2)
      af[k2] = *(const bf16x8*)&win[wave * 16 + lr][k2 * 32 + lg * 8];

    float m[4], Z[4], Zi[4];
#pragma unroll
    for (int r = 0; r < 4; ++r) { m[r] = -INFINITY; Z[r] = 0.f; }
    for (int ct = 0; ct < 4; ++ct) {
      f32x4 Ca = {0.f, 0.f, 0.f, 0.f}, Cb = {0.f, 0.f, 0.f, 0.f};
#pragma unroll
      for (int k2 = 0; k2 < 8; k2 += 2) {
        bf16x8 b0 = *(const bf16x8*)&win[ct * 16 + lr][k2 * 32 + lg * 8];
        bf16x8 b1 = *(const bf16x8*)&win[ct * 16 + lr][(k2 + 1) * 32 + lg * 8];
        Ca = __builtin_amdgcn_mfma_f32_16x16x32_bf16(af[k2], b0, Ca, 0, 0, 0);
        Cb = __builtin_amdgcn_mfma_f32_16x16x32_bf16(af[k2 + 1], b1, Cb, 0, 0, 0);
      }
#pragma unroll
      for (int r = 0; r < 4; ++r) {
        const float sv = (Ca[r] + Cb[r]) * 0.0625f;
        const float nm = fmaxf(m[r], sv);
        Z[r] = Z[r] * __expf(m[r] - nm) + __expf(sv - nm);
        m[r] = nm;
      }
    }
#pragma unroll
    for (int r = 0; r < 4; ++r) {
#pragma unroll
      for (int msk = 1; msk <= 8; msk <<= 1) {
        const float om = __shfl_xor(m[r], msk), oz = __shfl_xor(Z[r], msk);
        const float nm = fmaxf(m[r], om);
        Z[r] = Z[r] * __expf(m[r] - nm) + oz * __expf(om - nm);
        m[r] = nm;
      }
      Zi[r] = 1.f / Z[r];
    }
    for (int ct = 0; ct < 4; ++ct) {
      f32x4 Ca = {0.f, 0.f, 0.f, 0.f}, Cb = {0.f, 0.f, 0.f, 0.f};
#pragma unroll
      for (int k2 = 0; k2 < 8; k2 += 2) {
        bf16x8 b0 = *(const bf16x8*)&win[ct * 16 + lr][k2 * 32 + lg * 8];
        bf16x8 b1 = *(const bf16x8*)&win[ct * 16 + lr][(k2 + 1) * 32 + lg * 8];
        Ca = __builtin_amdgcn_mfma_f32_16x16x32_bf16(af[k2], b0, Ca, 0, 0, 0);
        Cb = __builtin_amdgcn_mfma_f32_16x16x32_bf16(af[k2 + 1], b1, Cb, 0, 0, 0);
      }
      float cs = 0.f;
#pragma unroll
      for (int r = 0; r < 4; ++r)
        cs += __expf((Ca[r] + Cb[r]) * 0.0625f - m[r]) * Zi[r];
      cs += __shfl_xor(cs, 16);
      cs += __shfl_xor(cs, 32);
      if (lg == 0) atomicAdd(&acc[ct * 16 + lr], cs);
    }
    __syncthreads();
    {
      const int d = tid;
      float s = 0.f;
#pragma unroll 8
      for (int k = 0; k < 64; ++k) s += acc[k] * bf2f(win[k][d]);
      p1[(size_t)l * D + d] = s * (1.f / 64.f);
    }
  } else {
    // ---- w = 16 path: 2 blocks/window (q-split); z selects p2a / p2b ----
    constexpr int nS = 7;
    const int zz = bid - NB4 - NB8;
    const int l = zz >> 1, z = zz & 1;
    const int lc = lane & 31, hi = lane >> 5;
    const int row0 = (l / nS) * 8, col0 = (l % nS) * 8;

    for (int e8 = tid; e8 < 256 * 32; e8 += 256) {
      const int t = e8 >> 5, c8 = (e8 & 31) * 8;
      const float* src = x + ((size_t)((row0 + (t >> 4)) * GRID + col0 + (t & 15))) * D + c8;
      *(bf16x8*)&win[t][c8] = pack8(*(const float4*)src, *(const float4*)(src + 4));
    }
    acc[tid] = 0.f;
    __syncthreads();

    const int R0 = (z * 4 + wave) * 32;
    bf16x8 af[16];
#pragma unroll
    for (int k2 = 0; k2 < 16; ++k2)
      af[k2] = *(const bf16x8*)&win[R0 + lc][k2 * 16 + hi * 8];

    float m[16], Z[16], Zi[16];
#pragma unroll
    for (int r = 0; r < 16; ++r) { m[r] = -INFINITY; Z[r] = 0.f; }

    for (int ct = 0; ct < 8; ++ct) {
      f32x16 Ca = {0.f,0.f,0.f,0.f,0.f,0.f,0.f,0.f,0.f,0.f,0.f,0.f,0.f,0.f,0.f,0.f};
      f32x16 Cb = Ca;
#pragma unroll
      for (int k2 = 0; k2 < 16; k2 += 2) {
        bf16x8 b0 = *(const bf16x8*)&win[ct * 32 + lc][k2 * 16 + hi * 8];
        bf16x8 b1 = *(const bf16x8*)&win[ct * 32 + lc][(k2 + 1) * 16 + hi * 8];
        Ca = __builtin_amdgcn_mfma_f32_32x32x16_bf16(af[k2], b0, Ca, 0, 0, 0);
        Cb = __builtin_amdgcn_mfma_f32_32x32x16_bf16(af[k2 + 1], b1, Cb, 0, 0, 0);
      }
#pragma unroll
      for (int r = 0; r < 16; ++r) {
        const float sv = (Ca[r] + Cb[r]) * 0.0625f;
        const float nm = fmaxf(m[r], sv);
        Z[r] = Z[r] * __expf(m[r] - nm) + __expf(sv - nm);
        m[r] = nm;
      }
    }
#pragma unroll
    for (int r = 0; r < 16; ++r) {
#pragma unroll
      for (int msk = 1; msk <= 16; msk <<= 1) {
        const float om = __shfl_xor(m[r], msk), oz = __shfl_xor(Z[r], msk);
        const float nm = fmaxf(m[r], om);
        Z[r] = Z[r] * __expf(m[r] - nm) + oz * __expf(om - nm);
        m[r] = nm;
      }
      Zi[r] = 1.f / Z[r];
    }

    for (int ct = 0; ct < 8; ++ct) {
      f32x16 Ca = {0.f,0.f,0.f,0.f,0.f,0.f,0.f,0.f,0.f,0.f,0.f,0.f,0.f,0.f,0.f,0.f};
      f32x16 Cb = Ca;
#pragma unroll
      for (int k2 = 0; k2 < 16; k2 += 2) {
        bf16x8 b0 = *(const bf16x8*)&win[ct * 32 + lc][k2 * 16 + hi * 8];
        bf16x8 b1 = *(const bf16x8*)&win[ct * 32 + lc][(k2 + 1) * 16 + hi * 8];
        Ca = __builtin_amdgcn_mfma_f32_32x32x16_bf16(af[k2], b0, Ca, 0, 0, 0);
        Cb = __builtin_amdgcn_mfma_f32_32x32x16_bf16(af[k2 + 1], b1, Cb, 0, 0, 0);
      }
      float cs = 0.f;
#pragma unroll
      for (int r = 0; r < 16; ++r)
        cs += __expf((Ca[r] + Cb[r]) * 0.0625f - m[r]) * Zi[r];
      cs += __shfl_xor(cs, 32);
      if (hi == 0) atomicAdd(&acc[ct * 32 + lc], cs);
    }
    __syncthreads();
    {
      const int d = tid;
      float s = 0.f;
#pragma unroll 8
      for (int k = 0; k < 256; ++k) s += acc[k] * bf2f(win[k][d]);
      float* dst = (z == 0) ? p2a : p2b;
      dst[(size_t)l * D + d] = s * (1.f / 256.f);
    }
  }
}

// ---------------------------------------------------------------------------
// Overlap-average scatter of pooled windows -> catb[t][768] (bf16)
// ---------------------------------------------------------------------------
DEVFN float gatherp(const float* __restrict__ pooled, int r, int c, int W, int s, int nS, int d) {
  int amin = max(0, (r - W + s) / s), amax = min(nS - 1, r / s);
  int bmin = max(0, (c - W + s) / s), bmax = min(nS - 1, c / s);
  float acc = 0.f;
  int cnt = 0;
  for (int a = amin; a <= amax; ++a)
    for (int b = bmin; b <= bmax; ++b) { acc += pooled[(size_t)(a * nS + b) * D + d]; ++cnt; }
  return acc / (float)cnt;
}

DEVFN float gatherp2(const float* __restrict__ pa, const float* __restrict__ pb,
                     int r, int c, int W, int s, int nS, int d) {
  int amin = max(0, (r - W + s) / s), amax = min(nS - 1, r / s);
  int bmin = max(0, (c - W + s) / s), bmax = min(nS - 1, c / s);
  float acc = 0.f;
  int cnt = 0;
  for (int a = amin; a <= amax; ++a)
    for (int b = bmin; b <= bmax; ++b) {
      const size_t i = (size_t)(a * nS + b) * D + d;
      acc += pa[i] + pb[i];
      ++cnt;
    }
  return acc / (float)cnt;
}

__global__ void k_combine(const float* __restrict__ p0, const float* __restrict__ p1,
                          const float* __restrict__ p2a, const float* __restrict__ p2b,
                          unsigned short* __restrict__ catb) {
  const int t = blockIdx.x, d = threadIdx.x;
  const int r = t >> 6, c = t & 63;
  unsigned short* o = catb + (size_t)t * 768;
  o[d]       = f2bf(gatherp(p0, r, c, 4, 2, 31, d));
  o[256 + d] = f2bf(gatherp(p1, r, c, 8, 4, 15, d));
  o[512 + d] = f2bf(gatherp2(p2a, p2b, r, c, 16, 8, 7, d));
}

// ---------------------------------------------------------------------------
// Block-wide sum of (a, b) over 256 threads
// ---------------------------------------------------------------------------
DEVFN float2 block_sum2(float a, float b) {
  __shared__ float sb[8];
#pragma unroll
  for (int m = 32; m; m >>= 1) { a += __shfl_xor(a, m); b += __shfl_xor(b, m); }
  const int w = threadIdx.x >> 6;
  __syncthreads();
  if ((threadIdx.x & 63) == 0) { sb[w] = a; sb[4 + w] = b; }
  __syncthreads();
  return make_float2(sb[0] + sb[1] + sb[2] + sb[3], sb[4] + sb[5] + sb[6] + sb[7]);
}

// out = LN(a (+ b)); optional bf16 dual write. In-place safe (out==a).
__global__ __launch_bounds__(256) void k_ln(float* __restrict__ out, unsigned short* __restrict__ outb,
                                            const float* __restrict__ a, const float* __restrict__ b,
                                            const float* __restrict__ g, const float* __restrict__ be) {
  const size_t i = (size_t)blockIdx.x * D + threadIdx.x;
  float v = a[i] + (b ? b[i] : 0.f);
  float2 s = block_sum2(v, v * v);
  float mean = s.x * (1.f / D);
  float var = s.y * (1.f / D) - mean * mean;
  const float r = (v - mean) * rsqrtf(var + 1e-5f) * g[threadIdx.x] + be[threadIdx.x];
  out[i] = r;
  if (outb) outb[i] = f2bf(r);
}

// xl = LN2(x + LN1(t1)); writes fp32 + bf16 (fuses the two post-fuse LNs)
__global__ __launch_bounds__(256) void k_ln_fuse(const float* __restrict__ t1,
                                                 const float* __restrict__ x,
                                                 float* __restrict__ xl,
                                                 unsigned short* __restrict__ xlb,
                                                 const float* __restrict__ fg,
                                                 const float* __restrict__ fbb,
                                                 const float* __restrict__ n1g,
                                                 const float* __restrict__ n1b) {
  const size_t i = (size_t)blockIdx.x * D + threadIdx.x;
  const float v1 = t1[i];
  float2 s1 = block_sum2(v1, v1 * v1);
  const float mean1 = s1.x * (1.f / D);
  const float var1 = s1.y * (1.f / D) - mean1 * mean1;
  const float r1 = (v1 - mean1) * rsqrtf(var1 + 1e-5f) * fg[threadIdx.x] + fbb[threadIdx.x];
  const float v2 = x[i] + r1;
  float2 s2 = block_sum2(v2, v2 * v2);
  const float mean2 = s2.x * (1.f / D);
  const float var2 = s2.y * (1.f / D) - mean2 * mean2;
  const float r2 = (v2 - mean2) * rsqrtf(var2 + 1e-5f) * n1g[threadIdx.x] + n1b[threadIdx.x];
  xl[i] = r2;
  xlb[i] = f2bf(r2);
}

// ---------------------------------------------------------------------------
// MFMA flash attention, split-KV x8: grid (S/64, NH, 8); 512 keys/block in
// eight FULLY-UNROLLED 64-key iterations (compile-time addresses / buffers).
// exp2-domain softmax; K LDS ping-pong [64][32]; V subtiled + tr-reads;
// defer-max (check even iters); split-l chains.
// ---------------------------------------------------------------------------
__global__ __launch_bounds__(256) void k_flash_mfma(const unsigned short* __restrict__ Qg,
                                                    const unsigned short* __restrict__ Kg,
                                                    const unsigned short* __restrict__ Vg,
                                                    unsigned short* __restrict__ po,
                                                    float* __restrict__ pml) {
  const int h = blockIdx.y, z = blockIdx.z;
  const int tid = threadIdx.x;
  const int wave = tid >> 6, lane = tid & 63;
  const int lr = lane & 15, lg = lane >> 4;
  constexpr int NT2 = 8;             // 8 iters x 64 keys = 512 keys per slice

  __shared__ unsigned short KS[2][64][32];
  __shared__ unsigned short VS[2][2048];

  const int q0 = blockIdx.x * 64 + wave * 16;
  const int kbase = z * 512;

  const bf16x8 qfrag = *(const bf16x8*)(Qg + (size_t)(q0 + lr) * D + h * DH + lg * 8);

  f32x4 o0 = {0.f, 0.f, 0.f, 0.f}, o1 = {0.f, 0.f, 0.f, 0.f};
  float mrow = -INFINITY, lrow = 0.f;

  const unsigned vsbase0 =
      (unsigned)(unsigned long long)(const void*)&VS[0][0] + (unsigned)(lg * 128 + lr * 2);

  const int key = tid >> 2, c8 = (tid & 3) * 8;
  const int vidx = (c8 >> 4) * 1024 + (key >> 2) * 64 + (key & 3) * 16 + (c8 & 15);
  const unsigned short* kp = Kg + (size_t)(kbase + key) * D + h * DH + c8;
  const unsigned short* vp = Vg + (size_t)(kbase + key) * D + h * DH + c8;
  constexpr int KSTEP = 64 * D;

  // prologue: stage tile 0 into buf 0
  {
    bf16x8 k0r = *(const bf16x8*)kp;
    bf16x8 v0r = *(const bf16x8*)vp;
    *(bf16x8*)&KS[0][key][c8] = k0r;
    *(bf16x8*)&VS[0][vidx] = v0r;
  }
  __syncthreads();

#pragma unroll
  for (int kt = 0; kt < NT2; ++kt) {
    const int cur = kt & 1;
    const int ktn = (kt + 1 < NT2) ? kt + 1 : kt;
    bf16x8 kreg = *(const bf16x8*)(kp + (size_t)ktn * KSTEP);
    bf16x8 vreg = *(const bf16x8*)(vp + (size_t)ktn * KSTEP);

    // swapped QK^T: s[k16][r] = S[q=lr][key = k16*16 + lg*4 + r] (log2 units)
    f32x4 s[4];
    __builtin_amdgcn_s_setprio(1);
#pragma unroll
    for (int k16 = 0; k16 < 4; ++k16) {
      bf16x8 ka = *(const bf16x8*)&KS[cur][k16 * 16 + lr][lg * 8];
      f32x4 zc = {0.f, 0.f, 0.f, 0.f};
      s[k16] = __builtin_amdgcn_mfma_f32_16x16x32_bf16(ka, qfrag, zc, 0, 0, 0);
    }
    __builtin_amdgcn_s_setprio(0);

    // issue V tr-reads early
    const unsigned vb = vsbase0 + (unsigned)(cur << 12);
    u32x2 tv000, tv001, tv010, tv011, tv100, tv101, tv110, tv111;
    asm volatile("ds_read_b64_tr_b16 %0, %1 offset:0"    : "=v"(tv000) : "v"(vb));
    asm volatile("ds_read_b64_tr_b16 %0, %1 offset:2048" : "=v"(tv001) : "v"(vb));
    asm volatile("ds_read_b64_tr_b16 %0, %1 offset:512"  : "=v"(tv010) : "v"(vb));
    asm volatile("ds_read_b64_tr_b16 %0, %1 offset:2560" : "=v"(tv011) : "v"(vb));
    asm volatile("ds_read_b64_tr_b16 %0, %1 offset:1024" : "=v"(tv100) : "v"(vb));
    asm volatile("ds_read_b64_tr_b16 %0, %1 offset:3072" : "=v"(tv101) : "v"(vb));
    asm volatile("ds_read_b64_tr_b16 %0, %1 offset:1536" : "=v"(tv110) : "v"(vb));
    asm volatile("ds_read_b64_tr_b16 %0, %1 offset:3584" : "=v"(tv111) : "v"(vb));

    // exp2-domain online softmax; defer-max checked every 2nd iter
    if ((kt & 1) == 0) {
      float tm = fmaxf(fmaxf(fmaxf(s[0][0], s[0][1]), fmaxf(s[0][2], s[0][3])),
                       fmaxf(fmaxf(s[1][0], s[1][1]), fmaxf(s[1][2], s[1][3])));
      tm = fmaxf(tm, fmaxf(fmaxf(fmaxf(s[2][0], s[2][1]), fmaxf(s[2][2], s[2][3])),
                           fmaxf(fmaxf(s[3][0], s[3][1]), fmaxf(s[3][2], s[3][3]))));
      const bool skip = __all(tm - mrow <= 11.f);
      if (!skip) {
        float tmm = fmaxf(tm, __shfl_xor(tm, 16));
        tmm = fmaxf(tmm, __shfl_xor(tmm, 32));
        const float nm = fmaxf(mrow, tmm);
        const float cfac = ex2(mrow - nm);
        mrow = nm;
        lrow *= cfac;
#pragma unroll
        for (int r = 0; r < 4; ++r) {
          const float cr = __shfl(cfac, lg * 4 + r);
          o0[r] *= cr; o1[r] *= cr;
        }
      }
    }
    // 4 independent accumulation chains
    float pa = 0.f, pb = 0.f, pc = 0.f, pd = 0.f;
#pragma unroll
    for (int k16 = 0; k16 < 4; ++k16) {
      s[k16][0] = ex2(s[k16][0] - mrow); pa += s[k16][0];
      s[k16][1] = ex2(s[k16][1] - mrow); pb += s[k16][1];
      s[k16][2] = ex2(s[k16][2] - mrow); pc += s[k16][2];
      s[k16][3] = ex2(s[k16][3] - mrow); pd += s[k16][3];
    }
    lrow += (pa + pb) + (pc + pd);

    asm volatile("s_waitcnt lgkmcnt(0)" ::: "memory");
    __builtin_amdgcn_sched_barrier(0);

    // PV: a = lane-local P (packed via cvt_pk), b = tr-read V fragments
    union VB { u32x2 u2[2]; bf16x8 b; };
    __builtin_amdgcn_s_setprio(1);
#pragma unroll
    for (int kt2 = 0; kt2 < 2; ++kt2) {
      union { unsigned w[4]; bf16x8 v; } pu;
      pu.w[0] = pk2(s[2 * kt2][0], s[2 * kt2][1]);
      pu.w[1] = pk2(s[2 * kt2][2], s[2 * kt2][3]);
      pu.w[2] = pk2(s[2 * kt2 + 1][0], s[2 * kt2 + 1][1]);
      pu.w[3] = pk2(s[2 * kt2 + 1][2], s[2 * kt2 + 1][3]);
      VB v0f, v1f;
      if (kt2 == 0) { v0f.u2[0] = tv000; v0f.u2[1] = tv010; v1f.u2[0] = tv001; v1f.u2[1] = tv011; }
      else          { v0f.u2[0] = tv100; v0f.u2[1] = tv110; v1f.u2[0] = tv101; v1f.u2[1] = tv111; }
      o0 = __builtin_amdgcn_mfma_f32_16x16x32_bf16(pu.v, v0f.b, o0, 0, 0, 0);
      o1 = __builtin_amdgcn_mfma_f32_16x16x32_bf16(pu.v, v1f.b, o1, 0, 0, 0);
    }
    __builtin_amdgcn_s_setprio(0);

    if (kt + 1 < NT2) {
      *(bf16x8*)&KS[cur ^ 1][key][c8] = kreg;
      *(bf16x8*)&VS[cur ^ 1][vidx] = vreg;
      __syncthreads();
    }
  }

  // single cross-lane l reduction (deferred from the loop)
  lrow += __shfl_xor(lrow, 16);
  lrow += __shfl_xor(lrow, 32);

  // partial outputs (unnormalized, bf16) + per-q (m [log2], l)
#pragma unroll
  for (int r = 0; r < 4; ++r) {
    unsigned short* op = po + (size_t)z * S * D + (size_t)(q0 + lg * 4 + r) * D + h * DH + lr;
    op[0]  = f2bf(o0[r]);
    op[16] = f2bf(o1[r]);
  }
  if (lane < 16) {
    float* mlp = pml + ((size_t)(z * NH + h) * S + q0 + lr) * 2;
    mlp[0] = mrow;
    mlp[1] = lrow;
  }
}

// merge the 8 KV slices: out bf16 t1b[q][d] (m in log2 domain)
__global__ __launch_bounds__(256) void k_fmerge(const unsigned short* __restrict__ po,
                                                const float* __restrict__ pml,
                                                unsigned short* __restrict__ t1b) {
  const int t = blockIdx.x, d = threadIdx.x;
  const int h = d >> 5;
  float m[NSPLIT], l[NSPLIT];
  float M = -INFINITY;
#pragma unroll
  for (int z = 0; z < NSPLIT; ++z) {
    const float* ml = pml + ((size_t)(z * NH + h) * S + t) * 2;
    m[z] = ml[0]; l[z] = ml[1];
    M = fmaxf(M, m[z]);
  }
  float L = 0.f, acc = 0.f;
#pragma unroll
  for (int z = 0; z < NSPLIT; ++z) {
    const float a = ex2(m[z] - M);
    L += l[z] * a;
    acc += bf2f(po[(size_t)z * S * D + (size_t)t * D + d]) * a;
  }
  t1b[(size_t)t * D + d] = f2bf(acc / L);
}

// ---------------------------------------------------------------------------
// Gate helpers (gate matvec+softmax fused into k_xf)
// ---------------------------------------------------------------------------
__global__ __launch_bounds__(256) void k_colmean(const float* __restrict__ xl,
                                                 const float* __restrict__ xg,
                                                 float* __restrict__ gbuf) {
  const int j = threadIdx.x;
  const int t0 = blockIdx.x * 16;
  float s = 0.f;
  for (int t = 0; t < 16; ++t) {
    size_t i = (size_t)(t0 + t) * D + j;
    s += xl[i] + xg[i];
  }
  atomicAdd(&gbuf[j], s * 0.5f);
}

__global__ __launch_bounds__(256) void k_xf(const float* __restrict__ xl,
                                            const float* __restrict__ xg,
                                            const float* __restrict__ gbuf,
                                            const float* __restrict__ gw,
                                            const float* __restrict__ gb,
                                            float* __restrict__ xf,
                                            unsigned short* __restrict__ xfb) {
  __shared__ float ab[2];
  {
    const int j = threadIdx.x;
    const float gm = gbuf[j] * (1.f / (float)S);
    float2 s = block_sum2(gm * gw[2 * j], gm * gw[2 * j + 1]);
    if (j == 0) {
      const float g0 = s.x + gb[0], g1 = s.y + gb[1];
      const float mx = fmaxf(g0, g1);
      const float e0 = __expf(g0 - mx), e1 = __expf(g1 - mx);
      ab[0] = e0 / (e0 + e1);
      ab[1] = e1 / (e0 + e1);
    }
    __syncthreads();
  }
  const float alpha = ab[0], beta = ab[1];
  const size_t i = ((size_t)blockIdx.x * 256 + threadIdx.x) * 4;
  float4 a = *(const float4*)(xg + i);
  float4 b = *(const float4*)(xl + i);
  float4 r;
  r.x = alpha * a.x + beta * b.x;
  r.y = alpha * a.y + beta * b.y;
  r.z = alpha * a.z + beta * b.z;
  r.w = alpha * a.w + beta * b.w;
  *(float4*)(xf + i) = r;
  *(uint2*)(xfb + i) = make_uint2(pk2(r.x, r.y), pk2(r.z, r.w));
}

// ===========================================================================
extern "C" void kernel_launch(void* const* d_in, const int* in_sizes, int n_in,
                              void* d_out, int out_size, void* d_ws, size_t ws_size,
                              hipStream_t stream) {
  const float* x   = (const float*)d_in[0];
  const float* fw  = (const float*)d_in[2];
  const float* fb  = (const float*)d_in[3];
  const float* fg  = (const float*)d_in[4];
  const float* fbb = (const float*)d_in[5];
  const float* wq  = (const float*)d_in[6];
  const float* wk  = (const float*)d_in[7];
  const float* wv  = (const float*)d_in[8];
  const float* bq  = (const float*)d_in[9];
  const float* bk  = (const float*)d_in[10];
  const float* bv  = (const float*)d_in[11];
  const float* wo  = (const float*)d_in[12];
  const float* bo  = (const float*)d_in[13];
  const float* gw  = (const float*)d_in[14];
  const float* gb  = (const float*)d_in[15];
  const float* w1  = (const float*)d_in[16];
  const float* b1  = (const float*)d_in[17];
  const float* w2  = (const float*)d_in[18];
  const float* b2  = (const float*)d_in[19];
  const float* n1g = (const float*)d_in[20];
  const float* n1b = (const float*)d_in[21];
  const float* n2g = (const float*)d_in[22];
  const float* n2b = (const float*)d_in[23];
  const float* n3g = (const float*)d_in[24];
  const float* n3b = (const float*)d_in[25];
  float* out = (float*)d_out;

  // ---- workspace carve (bytes) ----
  char* base = (char*)d_ws;
  size_t off = 0;
  auto carve = [&](size_t bytes) { char* p = base + off; off += (bytes + 255) & ~(size_t)255; return p; };
  float* p0  = (float*)carve(961 * 256 * 4);
  float* p1  = (float*)carve(225 * 256 * 4);
  float* p2a = (float*)carve(49 * 256 * 4);
  float* p2b = (float*)carve(49 * 256 * 4);
  unsigned short* fwT = (unsigned short*)carve(256 * 768 * 2);
  unsigned short* wqkvT = (unsigned short*)carve(3 * 256 * 256 * 2);  // q|k|v
  unsigned short* wqT = wqkvT;
  unsigned short* wkT = wqkvT + 256 * 256;
  unsigned short* wvT = wqkvT + 2 * 256 * 256;
  unsigned short* woT = (unsigned short*)carve(256 * 256 * 2);
  unsigned short* w1T = (unsigned short*)carve(1024 * 256 * 2);
  unsigned short* w2T = (unsigned short*)carve(256 * 1024 * 2);
  char* R = carve(8388608);   // catb(6.3MB) -> xg(4MB) -> hbuf(8MB)
  unsigned short* catb = (unsigned short*)R;
  float* xg            = (float*)R;
  unsigned short* hbuf = (unsigned short*)R;
  unsigned short* po = (unsigned short*)carve((size_t)NSPLIT * S * D * 2);  // 16MB
  float* pml = (float*)carve((size_t)NSPLIT * NH * S * 2 * 4);
  unsigned short* qb = (unsigned short*)carve((size_t)S * D * 2);
  unsigned short* kb = (unsigned short*)carve((size_t)S * D * 2);
  unsigned short* vb = (unsigned short*)carve((size_t)S * D * 2);
  float* xf            = (float*)qb;             // qb+kb region, dead after flash
  unsigned short* xfb  = vb;                     // vb region, dead after flash
  float* t1  = (float*)carve((size_t)S * D * 4); // fuse out; later ffo
  float* ffo = t1;
  unsigned short* t1b = (unsigned short*)carve((size_t)S * D * 2);
  float* xl  = (float*)carve((size_t)S * D * 4);
  unsigned short* xlb = (unsigned short*)carve((size_t)S * D * 2);
  float* gbuf = (float*)carve(264 * 4);

  hipMemsetAsync(gbuf, 0, 264 * sizeof(float), stream);

  // weight pre-transpose (bf16 WT[N][K]; wq/wk/wv contiguous)
  k_wt<<<dim3(960), dim3(256), 0, stream>>>(fw, wq, wk, wv, wo, w1, w2,
                                            fwT, wqT, wkT, wvT, woT, w1T, w2T);
  // local multi-scale window attention (single merged dispatch; p2 dual-buf)
  k_local_all<<<dim3(NB4 + NB8 + NB16), dim3(256), 0, stream>>>(x, p0, p1, p2a, p2b);
  // scatter/avg -> catb[S][768] bf16
  k_combine<<<dim3(S), dim3(256), 0, stream>>>(p0, p1, p2a, p2b, catb);
  // fuse GEMM + fused LN pair
  k_gemm_m<768, 0, 0><<<dim3(S / 64, 4), dim3(64), 0, stream>>>(catb, fwT, fb, t1, 256);
  k_ln_fuse<<<dim3(S), dim3(256), 0, stream>>>(t1, x, xl, xlb, fg, fbb, n1g, n1b);
  // global MHA (bf16 q/k/v; single QKV dispatch; q pre-scaled w/ log2e)
  k_gemm_qkv<<<dim3(S / 64, 12), dim3(64), 0, stream>>>(xlb, wqkvT, bq, bk, bv, qb, kb, vb);
  k_flash_mfma<<<dim3(S / 64, NH, NSPLIT), dim3(256), 0, stream>>>(qb, kb, vb, po, pml);
  k_fmerge<<<dim3(S), dim3(256), 0, stream>>>(po, pml, t1b);
  k_gemm_m<256, 0, 0><<<dim3(S / 64, 4), dim3(64), 0, stream>>>(t1b, woT, bo, xf, 256);
  k_ln<<<dim3(S), dim3(256), 0, stream>>>(xg, nullptr, xl, xf, n2g, n2b);
  // gate (mean via atomics; matvec+softmax fused into k_xf)
  k_colmean<<<dim3(256), dim3(256), 0, stream>>>(xl, xg, gbuf);
  k_xf<<<dim3(S * D / 1024), dim3(256), 0, stream>>>(xl, xg, gbuf, gw, gb, xf, xfb);
  // FFN + final LN
  k_gemm_m<256, 1, 1><<<dim3(S / 64, 16), dim3(64), 0, stream>>>(xfb, w1T, b1, hbuf, 1024);
  k_gemm_m<1024, 0, 0><<<dim3(S / 64, 4), dim3(64), 0, stream>>>(hbuf, w2T, b2, ffo, 256);
  k_ln<<<dim3(S), dim3(256), 0, stream>>>(out, nullptr, xf, ffo, n3g, n3b);
}

// Round 18
// 199.147 us; speedup vs baseline: 1.0239x; 1.0185x over previous
//
#include <hip/hip_runtime.h>
#include <hip/hip_bf16.h>
#include <cstdint>
#include <cstddef>

// ============================================================================
// HierarchicalTransformerBlock: B=1, S=4096 (64x64 grid), D=256, NH=8, dh=32,
// DFF=1024, local windows w = 4,8,16 (stride w/2).
// Round 18: NSPLIT back to 4 (flash time shown split-invariant in r12/r14 A/B;
// halves po write + fmerge read traffic). Keeps r16 half-rate max-check,
// r15 64x64 GEMMs, r17 p2 double-buffer. Flash loop runtime (NT2=16).
// ============================================================================

#define DEVFN __device__ __forceinline__

constexpr int S    = 4096;
constexpr int D    = 256;
constexpr int GRID = 64;
constexpr int NH   = 8;
constexpr int DH   = 32;
constexpr int NSPLIT = 4;

typedef __attribute__((ext_vector_type(8))) short bf16x8;
typedef __attribute__((ext_vector_type(4))) float f32x4;
typedef __attribute__((ext_vector_type(16))) float f32x16;
typedef __attribute__((ext_vector_type(2))) unsigned int u32x2;

DEVFN float asf(unsigned u) { return __uint_as_float(u); }

DEVFN unsigned short f2bf(float f) {  // round-to-nearest-even bf16
  unsigned u = __float_as_uint(f);
  u += 0x7fffu + ((u >> 16) & 1u);
  return (unsigned short)(u >> 16);
}
DEVFN float bf2f(unsigned short s) { return __uint_as_float(((unsigned)s) << 16); }

DEVFN unsigned pk2(float a, float b) {  // packed HW cvt (v_cvt_pk_bf16_f32)
  __hip_bfloat162 h = __float22bfloat162_rn(make_float2(a, b));
  return *(unsigned*)&h;
}

DEVFN bf16x8 pack8(float4 a, float4 b) {
  union { unsigned w[4]; bf16x8 v; } u;
  u.w[0] = pk2(a.x, a.y); u.w[1] = pk2(a.z, a.w);
  u.w[2] = pk2(b.x, b.y); u.w[3] = pk2(b.z, b.w);
  return u.v;
}

DEVFN float ex2(float x) {  // 2^x
#if __has_builtin(__builtin_amdgcn_exp2f)
  return __builtin_amdgcn_exp2f(x);
#else
  return __expf(x * 0.6931471805599453f);
#endif
}

DEVFN float gelu_t(float u) {  // tanh-form GELU (|err| <= ~3e-3 vs exact)
  const float y = 0.7978845608028654f * (u + 0.044715f * u * u * u);
  const float e = __expf(2.f * y);
  return 0.5f * u * (2.f - 2.f / (e + 1.f));
}

// ---------------------------------------------------------------------------
// Weight pre-transpose: fp32 W[K][N] -> bf16 WT[N][K]; 32x32 tiles via LDS.
// ---------------------------------------------------------------------------
__global__ __launch_bounds__(256) void k_wt(
    const float* fw, const float* wq, const float* wk, const float* wv,
    const float* wo, const float* w1, const float* w2,
    unsigned short* fwT, unsigned short* wqT, unsigned short* wkT,
    unsigned short* wvT, unsigned short* woT, unsigned short* w1T,
    unsigned short* w2T) {
  __shared__ unsigned short tile[32][36];
  const int bid = blockIdx.x;
  const float* src; unsigned short* dst; int K, N, t;
  if (bid < 192)      { src = fw; dst = fwT; K = 768;  N = 256;  t = bid; }
  else if (bid < 256) { src = wq; dst = wqT; K = 256;  N = 256;  t = bid - 192; }
  else if (bid < 320) { src = wk; dst = wkT; K = 256;  N = 256;  t = bid - 256; }
  else if (bid < 384) { src = wv; dst = wvT; K = 256;  N = 256;  t = bid - 320; }
  else if (bid < 448) { src = wo; dst = woT; K = 256;  N = 256;  t = bid - 384; }
  else if (bid < 704) { src = w1; dst = w1T; K = 256;  N = 1024; t = bid - 448; }
  else                { src = w2; dst = w2T; K = 1024; N = 256;  t = bid - 704; }
  const int nkt = K >> 5;
  const int k0 = (t % nkt) * 32, n0 = (t / nkt) * 32;
  const int i = threadIdx.x >> 3, j4 = threadIdx.x & 7;
  const float4 v = *(const float4*)(src + (size_t)(k0 + i) * N + n0 + j4 * 4);
  *(uint2*)&tile[i][j4 * 4] = make_uint2(pk2(v.x, v.y), pk2(v.z, v.w));
  __syncthreads();
  unsigned o0 = tile[j4 * 4 + 0][i], o1 = tile[j4 * 4 + 1][i];
  unsigned o2 = tile[j4 * 4 + 2][i], o3 = tile[j4 * 4 + 3][i];
  *(uint2*)(dst + (size_t)(n0 + i) * K + k0 + j4 * 4) =
      make_uint2(o0 | (o1 << 16), o2 | (o3 << 16));
}

// ---------------------------------------------------------------------------
// MFMA GEMM: C[M][N] = Ab[M][K](bf16) @ WT[N][K]^T(bf16) + bias.
// Wave computes 64x64 (2x2 grid of 32x32 tiles, 4 independent MFMA chains,
// 1:1 load:MFMA). Grid (M/64, N/64).
// ---------------------------------------------------------------------------
template <int K, int OUTBF, int ACT>
__global__ __launch_bounds__(64) void k_gemm_m(const unsigned short* __restrict__ Ab,
                                               const unsigned short* __restrict__ WT,
                                               const float* __restrict__ bias,
                                               void* __restrict__ Cout, int N) {
  const int lane = threadIdx.x;
  const int lc = lane & 31, hi = lane >> 5;
  const int m0 = blockIdx.x * 64, n0 = blockIdx.y * 64;
  const unsigned short* ap0 = Ab + (size_t)(m0 + lc) * K + hi * 8;
  const unsigned short* ap1 = Ab + (size_t)(m0 + 32 + lc) * K + hi * 8;
  const unsigned short* bp0 = WT + (size_t)(n0 + lc) * K + hi * 8;
  const unsigned short* bp1 = WT + (size_t)(n0 + 32 + lc) * K + hi * 8;
  f32x16 acc00 = {0.f,0.f,0.f,0.f,0.f,0.f,0.f,0.f,0.f,0.f,0.f,0.f,0.f,0.f,0.f,0.f};
  f32x16 acc01 = acc00, acc10 = acc00, acc11 = acc00;
#pragma unroll 4
  for (int k0 = 0; k0 < K; k0 += 16) {
    bf16x8 a0 = *(const bf16x8*)(ap0 + k0);
    bf16x8 a1 = *(const bf16x8*)(ap1 + k0);
    bf16x8 b0 = *(const bf16x8*)(bp0 + k0);
    bf16x8 b1 = *(const bf16x8*)(bp1 + k0);
    acc00 = __builtin_amdgcn_mfma_f32_32x32x16_bf16(a0, b0, acc00, 0, 0, 0);
    acc01 = __builtin_amdgcn_mfma_f32_32x32x16_bf16(a0, b1, acc01, 0, 0, 0);
    acc10 = __builtin_amdgcn_mfma_f32_32x32x16_bf16(a1, b0, acc10, 0, 0, 0);
    acc11 = __builtin_amdgcn_mfma_f32_32x32x16_bf16(a1, b1, acc11, 0, 0, 0);
  }
  const float bv0 = bias[n0 + lc], bv1 = bias[n0 + 32 + lc];
#pragma unroll
  for (int r = 0; r < 16; ++r) {
    const int row = (r & 3) + 8 * (r >> 2) + 4 * hi;
    float v00 = acc00[r] + bv0;
    float v01 = acc01[r] + bv1;
    float v10 = acc10[r] + bv0;
    float v11 = acc11[r] + bv1;
    if (ACT == 1) { v00 = gelu_t(v00); v01 = gelu_t(v01); v10 = gelu_t(v10); v11 = gelu_t(v11); }
    if (OUTBF) {
      unsigned short* c = (unsigned short*)Cout;
      c[(size_t)(m0 + row) * N + n0 + lc]           = f2bf(v00);
      c[(size_t)(m0 + row) * N + n0 + 32 + lc]      = f2bf(v01);
      c[(size_t)(m0 + 32 + row) * N + n0 + lc]      = f2bf(v10);
      c[(size_t)(m0 + 32 + row) * N + n0 + 32 + lc] = f2bf(v11);
    } else {
      float* c = (float*)Cout;
      c[(size_t)(m0 + row) * N + n0 + lc]           = v00;
      c[(size_t)(m0 + row) * N + n0 + 32 + lc]      = v01;
      c[(size_t)(m0 + 32 + row) * N + n0 + lc]      = v10;
      c[(size_t)(m0 + 32 + row) * N + n0 + 32 + lc] = v11;
    }
  }
}

// QKV: grid (S/64, 12); sel = by>>2, n0 = (by&3)*64. Q pre-scaled by
// log2(e)/sqrt(dh). Wave computes 64x64.
__global__ __launch_bounds__(64) void k_gemm_qkv(const unsigned short* __restrict__ Ab,
                                                 const unsigned short* __restrict__ wqkvT,
                                                 const float* __restrict__ bq,
                                                 const float* __restrict__ bk,
                                                 const float* __restrict__ bv,
                                                 unsigned short* __restrict__ qb,
                                                 unsigned short* __restrict__ kb,
                                                 unsigned short* __restrict__ vb) {
  const int lane = threadIdx.x;
  const int lc = lane & 31, hi = lane >> 5;
  const int m0 = blockIdx.x * 64;
  const int sel = blockIdx.y >> 2, n0 = (blockIdx.y & 3) * 64;
  const unsigned short* WT = wqkvT + (size_t)sel * 256 * 256;
  const float* bias = sel == 0 ? bq : sel == 1 ? bk : bv;
  unsigned short* out = sel == 0 ? qb : sel == 1 ? kb : vb;
  const float oscale = sel == 0 ? 0.25505889254f : 1.f;  // (1/sqrt(32))*log2(e)
  const unsigned short* ap0 = Ab + (size_t)(m0 + lc) * 256 + hi * 8;
  const unsigned short* ap1 = Ab + (size_t)(m0 + 32 + lc) * 256 + hi * 8;
  const unsigned short* bp0 = WT + (size_t)(n0 + lc) * 256 + hi * 8;
  const unsigned short* bp1 = WT + (size_t)(n0 + 32 + lc) * 256 + hi * 8;
  f32x16 acc00 = {0.f,0.f,0.f,0.f,0.f,0.f,0.f,0.f,0.f,0.f,0.f,0.f,0.f,0.f,0.f,0.f};
  f32x16 acc01 = acc00, acc10 = acc00, acc11 = acc00;
#pragma unroll 4
  for (int k0 = 0; k0 < 256; k0 += 16) {
    bf16x8 a0 = *(const bf16x8*)(ap0 + k0);
    bf16x8 a1 = *(const bf16x8*)(ap1 + k0);
    bf16x8 b0 = *(const bf16x8*)(bp0 + k0);
    bf16x8 b1 = *(const bf16x8*)(bp1 + k0);
    acc00 = __builtin_amdgcn_mfma_f32_32x32x16_bf16(a0, b0, acc00, 0, 0, 0);
    acc01 = __builtin_amdgcn_mfma_f32_32x32x16_bf16(a0, b1, acc01, 0, 0, 0);
    acc10 = __builtin_amdgcn_mfma_f32_32x32x16_bf16(a1, b0, acc10, 0, 0, 0);
    acc11 = __builtin_amdgcn_mfma_f32_32x32x16_bf16(a1, b1, acc11, 0, 0, 0);
  }
  const float bv0 = bias[n0 + lc], bv1 = bias[n0 + 32 + lc];
#pragma unroll
  for (int r = 0; r < 16; ++r) {
    const int row = (r & 3) + 8 * (r >> 2) + 4 * hi;
    out[(size_t)(m0 + row) * 256 + n0 + lc]           = f2bf((acc00[r] + bv0) * oscale);
    out[(size_t)(m0 + row) * 256 + n0 + 32 + lc]      = f2bf((acc01[r] + bv1) * oscale);
    out[(size_t)(m0 + 32 + row) * 256 + n0 + lc]      = f2bf((acc10[r] + bv0) * oscale);
    out[(size_t)(m0 + 32 + row) * 256 + n0 + 32 + lc] = f2bf((acc11[r] + bv1) * oscale);
  }
}

// ---------------------------------------------------------------------------
// Merged local windowed attention: ONE dispatch, 564 blocks x 256 threads.
// w16 path: z=0 writes p2a, z=1 writes p2b (both plain stores; combined later).
// ---------------------------------------------------------------------------
constexpr int NB4 = 241, NB8 = 225, NB16 = 98;

__global__ __launch_bounds__(256, 1) void k_local_all(const float* __restrict__ x,
                                                      float* __restrict__ p0,
                                                      float* __restrict__ p1,
                                                      float* __restrict__ p2a,
                                                      float* __restrict__ p2b) {
  constexpr int LDE = 264;
  __shared__ unsigned short win[256][LDE];
  __shared__ float acc[256];
  const int bid = blockIdx.x;
  const int tid = threadIdx.x;
  const int wave = tid >> 6, lane = tid & 63;

  if (bid < NB4) {
    // ---- w = 4 path: per-wave window, no cross-wave sync ----
    constexpr int nS = 31;
    const int widx = bid * 4 + wave;
    if (widx < 961) {
      const int lr = lane & 15, lg = lane >> 4;
      const int row0 = (widx / nS) * 2, col0 = (widx % nS) * 2;
      unsigned short(*w4)[LDE] = &win[wave * 16];
      float* a4 = &acc[wave * 16];
      for (int e8 = lane; e8 < 16 * 32; e8 += 64) {
        const int t = e8 >> 5, c8 = (e8 & 31) * 8;
        const float* src = x + ((size_t)((row0 + (t >> 2)) * GRID + col0 + (t & 3))) * D + c8;
        *(bf16x8*)&w4[t][c8] = pack8(*(const float4*)src, *(const float4*)(src + 4));
      }
      if (lane < 16) a4[lane] = 0.f;
      asm volatile("s_waitcnt lgkmcnt(0)" ::: "memory");

      bf16x8 af[8];
#pragma unroll
      for (int k2 = 0; k2 < 8; ++k2)
        af[k2] = *(const bf16x8*)&w4[lr][k2 * 32 + lg * 8];

      float m[4], Z[4], Zi[4];
#pragma unroll
      for (int r = 0; r < 4; ++r) { m[r] = -INFINITY; Z[r] = 0.f; }
      {
        f32x4 Ca = {0.f, 0.f, 0.f, 0.f}, Cb = {0.f, 0.f, 0.f, 0.f};
#pragma unroll
        for (int k2 = 0; k2 < 8; k2 += 2) {
          bf16x8 b0 = *(const bf16x8*)&w4[lr][k2 * 32 + lg * 8];
          bf16x8 b1 = *(const bf16x8*)&w4[lr][(k2 + 1) * 32 + lg * 8];
          Ca = __builtin_amdgcn_mfma_f32_16x16x32_bf16(af[k2], b0, Ca, 0, 0, 0);
          Cb = __builtin_amdgcn_mfma_f32_16x16x32_bf16(af[k2 + 1], b1, Cb, 0, 0, 0);
        }
#pragma unroll
        for (int r = 0; r < 4; ++r) {
          const float sv = (Ca[r] + Cb[r]) * 0.0625f;
          const float nm = fmaxf(m[r], sv);
          Z[r] = Z[r] * __expf(m[r] - nm) + __expf(sv - nm);
          m[r] = nm;
        }
      }
#pragma unroll
      for (int r = 0; r < 4; ++r) {
#pragma unroll
        for (int msk = 1; msk <= 8; msk <<= 1) {
          const float om = __shfl_xor(m[r], msk), oz = __shfl_xor(Z[r], msk);
          const float nm = fmaxf(m[r], om);
          Z[r] = Z[r] * __expf(m[r] - nm) + oz * __expf(om - nm);
          m[r] = nm;
        }
        Zi[r] = 1.f / Z[r];
      }
      {
        f32x4 Ca = {0.f, 0.f, 0.f, 0.f}, Cb = {0.f, 0.f, 0.f, 0.f};
#pragma unroll
        for (int k2 = 0; k2 < 8; k2 += 2) {
          bf16x8 b0 = *(const bf16x8*)&w4[lr][k2 * 32 + lg * 8];
          bf16x8 b1 = *(const bf16x8*)&w4[lr][(k2 + 1) * 32 + lg * 8];
          Ca = __builtin_amdgcn_mfma_f32_16x16x32_bf16(af[k2], b0, Ca, 0, 0, 0);
          Cb = __builtin_amdgcn_mfma_f32_16x16x32_bf16(af[k2 + 1], b1, Cb, 0, 0, 0);
        }
        float cs = 0.f;
#pragma unroll
        for (int r = 0; r < 4; ++r)
          cs += __expf((Ca[r] + Cb[r]) * 0.0625f - m[r]) * Zi[r];
        cs += __shfl_xor(cs, 16);
        cs += __shfl_xor(cs, 32);
        if (lg == 0) atomicAdd(&a4[lr], cs);
      }
      asm volatile("s_waitcnt lgkmcnt(0)" ::: "memory");
      for (int d = lane; d < D; d += 64) {
        float s = 0.f;
#pragma unroll
        for (int k = 0; k < 16; ++k) s += a4[k] * bf2f(w4[k][d]);
        p0[(size_t)widx * D + d] = s * (1.f / 16.f);
      }
    }
  } else if (bid < NB4 + NB8) {
    // ---- w = 8 path: one window/block ----
    constexpr int nS = 15;
    const int l = bid - NB4;
    const int lr = lane & 15, lg = lane >> 4;
    const int row0 = (l / nS) * 4, col0 = (l % nS) * 4;
    for (int e8 = tid; e8 < 64 * 32; e8 += 256) {
      const int t = e8 >> 5, c8 = (e8 & 31) * 8;
      const float* src = x + ((size_t)((row0 + (t >> 3)) * GRID + col0 + (t & 7))) * D + c8;
      *(bf16x8*)&win[t][c8] = pack8(*(const float4*)src, *(const float4*)(src + 4));
    }
    if (tid < 64) acc[tid] = 0.f;
    __syncthreads();

    bf16x8 af[8];
#pragma unroll
    for (int k2 = 0; k2 < 8; ++k2)
      af[k2] = *(const bf16x8*)&win[wave * 16 + lr][k2 * 32 + lg * 8];

    float m[4], Z[4], Zi[4];
#pragma unroll
    for (int r = 0; r < 4; ++r) { m[r] = -INFINITY; Z[r] = 0.f; }
    for (int ct = 0; ct < 4; ++ct) {
      f32x4 Ca = {0.f, 0.f, 0.f, 0.f}, Cb = {0.f, 0.f, 0.f, 0.f};
#pragma unroll
      for (int k2 = 0; k2 < 8; k2 += 2) {
        bf16x8 b0 = *(const bf16x8*)&win[ct * 16 + lr][k2 * 32 + lg * 8];
        bf16x8 b1 = *(const bf16x8*)&win[ct * 16 + lr][(k2 + 1) * 32 + lg * 8];
        Ca = __builtin_amdgcn_mfma_f32_16x16x32_bf16(af[k2], b0, Ca, 0, 0, 0);
        Cb = __builtin_amdgcn_mfma_f32_16x16x32_bf16(af[k2 + 1], b1, Cb, 0, 0, 0);
      }
#pragma unroll
      for (int r = 0; r < 4; ++r) {
        const float sv = (Ca[r] + Cb[r]) * 0.0625f;
        const float nm = fmaxf(m[r], sv);
        Z[r] = Z[r] * __expf(m[r] - nm) + __expf(sv - nm);
        m[r] = nm;
      }
    }
#pragma unroll
    for (int r = 0; r < 4; ++r) {
#pragma unroll
      for (int msk = 1; msk <= 8; msk <<= 1) {
        const float om = __shfl_xor(m[r], msk), oz = __shfl_xor(Z[r], msk);
        const float nm = fmaxf(m[r], om);
        Z[r] = Z[r] * __expf(m[r] - nm) + oz * __expf(om - nm);
        m[r] = nm;
      }
      Zi[r] = 1.f / Z[r];
    }
    for (int ct = 0; ct < 4; ++ct) {
      f32x4 Ca = {0.f, 0.f, 0.f, 0.f}, Cb = {0.f, 0.f, 0.f, 0.f};
#pragma unroll
      for (int k2 = 0; k2 < 8; k2 += 2) {
        bf16x8 b0 = *(const bf16x8*)&win[ct * 16 + lr][k2 * 32 + lg * 8];
        bf16x8 b1 = *(const bf16x8*)&win[ct * 16 + lr][(k2 + 1) * 32 + lg * 8];
        Ca = __builtin_amdgcn_mfma_f32_16x16x32_bf16(af[k2], b0, Ca, 0, 0, 0);
        Cb = __builtin_amdgcn_mfma_f32_16x16x32_bf16(af[k2 + 1], b1, Cb, 0, 0, 0);
      }
      float cs = 0.f;
#pragma unroll
      for (int r = 0; r < 4; ++r)
        cs += __expf((Ca[r] + Cb[r]) * 0.0625f - m[r]) * Zi[r];
      cs += __shfl_xor(cs, 16);
      cs += __shfl_xor(cs, 32);
      if (lg == 0) atomicAdd(&acc[ct * 16 + lr], cs);
    }
    __syncthreads();
    {
      const int d = tid;
      float s = 0.f;
#pragma unroll 8
      for (int k = 0; k < 64; ++k) s += acc[k] * bf2f(win[k][d]);
      p1[(size_t)l * D + d] = s * (1.f / 64.f);
    }
  } else {
    // ---- w = 16 path: 2 blocks/window (q-split); z selects p2a / p2b ----
    constexpr int nS = 7;
    const int zz = bid - NB4 - NB8;
    const int l = zz >> 1, z = zz & 1;
    const int lc = lane & 31, hi = lane >> 5;
    const int row0 = (l / nS) * 8, col0 = (l % nS) * 8;

    for (int e8 = tid; e8 < 256 * 32; e8 += 256) {
      const int t = e8 >> 5, c8 = (e8 & 31) * 8;
      const float* src = x + ((size_t)((row0 + (t >> 4)) * GRID + col0 + (t & 15))) * D + c8;
      *(bf16x8*)&win[t][c8] = pack8(*(const float4*)src, *(const float4*)(src + 4));
    }
    acc[tid] = 0.f;
    __syncthreads();

    const int R0 = (z * 4 + wave) * 32;
    bf16x8 af[16];
#pragma unroll
    for (int k2 = 0; k2 < 16; ++k2)
      af[k2] = *(const bf16x8*)&win[R0 + lc][k2 * 16 + hi * 8];

    float m[16], Z[16], Zi[16];
#pragma unroll
    for (int r = 0; r < 16; ++r) { m[r] = -INFINITY; Z[r] = 0.f; }

    for (int ct = 0; ct < 8; ++ct) {
      f32x16 Ca = {0.f,0.f,0.f,0.f,0.f,0.f,0.f,0.f,0.f,0.f,0.f,0.f,0.f,0.f,0.f,0.f};
      f32x16 Cb = Ca;
#pragma unroll
      for (int k2 = 0; k2 < 16; k2 += 2) {
        bf16x8 b0 = *(const bf16x8*)&win[ct * 32 + lc][k2 * 16 + hi * 8];
        bf16x8 b1 = *(const bf16x8*)&win[ct * 32 + lc][(k2 + 1) * 16 + hi * 8];
        Ca = __builtin_amdgcn_mfma_f32_32x32x16_bf16(af[k2], b0, Ca, 0, 0, 0);
        Cb = __builtin_amdgcn_mfma_f32_32x32x16_bf16(af[k2 + 1], b1, Cb, 0, 0, 0);
      }
#pragma unroll
      for (int r = 0; r < 16; ++r) {
        const float sv = (Ca[r] + Cb[r]) * 0.0625f;
        const float nm = fmaxf(m[r], sv);
        Z[r] = Z[r] * __expf(m[r] - nm) + __expf(sv - nm);
        m[r] = nm;
      }
    }
#pragma unroll
    for (int r = 0; r < 16; ++r) {
#pragma unroll
      for (int msk = 1; msk <= 16; msk <<= 1) {
        const float om = __shfl_xor(m[r], msk), oz = __shfl_xor(Z[r], msk);
        const float nm = fmaxf(m[r], om);
        Z[r] = Z[r] * __expf(m[r] - nm) + oz * __expf(om - nm);
        m[r] = nm;
      }
      Zi[r] = 1.f / Z[r];
    }

    for (int ct = 0; ct < 8; ++ct) {
      f32x16 Ca = {0.f,0.f,0.f,0.f,0.f,0.f,0.f,0.f,0.f,0.f,0.f,0.f,0.f,0.f,0.f,0.f};
      f32x16 Cb = Ca;
#pragma unroll
      for (int k2 = 0; k2 < 16; k2 += 2) {
        bf16x8 b0 = *(const bf16x8*)&win[ct * 32 + lc][k2 * 16 + hi * 8];
        bf16x8 b1 = *(const bf16x8*)&win[ct * 32 + lc][(k2 + 1) * 16 + hi * 8];
        Ca = __builtin_amdgcn_mfma_f32_32x32x16_bf16(af[k2], b0, Ca, 0, 0, 0);
        Cb = __builtin_amdgcn_mfma_f32_32x32x16_bf16(af[k2 + 1], b1, Cb, 0, 0, 0);
      }
      float cs = 0.f;
#pragma unroll
      for (int r = 0; r < 16; ++r)
        cs += __expf((Ca[r] + Cb[r]) * 0.0625f - m[r]) * Zi[r];
      cs += __shfl_xor(cs, 32);
      if (hi == 0) atomicAdd(&acc[ct * 32 + lc], cs);
    }
    __syncthreads();
    {
      const int d = tid;
      float s = 0.f;
#pragma unroll 8
      for (int k = 0; k < 256; ++k) s += acc[k] * bf2f(win[k][d]);
      float* dst = (z == 0) ? p2a : p2b;
      dst[(size_t)l * D + d] = s * (1.f / 256.f);
    }
  }
}

// ---------------------------------------------------------------------------
// Overlap-average scatter of pooled windows -> catb[t][768] (bf16)
// ---------------------------------------------------------------------------
DEVFN float gatherp(const float* __restrict__ pooled, int r, int c, int W, int s, int nS, int d) {
  int amin = max(0, (r - W + s) / s), amax = min(nS - 1, r / s);
  int bmin = max(0, (c - W + s) / s), bmax = min(nS - 1, c / s);
  float acc = 0.f;
  int cnt = 0;
  for (int a = amin; a <= amax; ++a)
    for (int b = bmin; b <= bmax; ++b) { acc += pooled[(size_t)(a * nS + b) * D + d]; ++cnt; }
  return acc / (float)cnt;
}

DEVFN float gatherp2(const float* __restrict__ pa, const float* __restrict__ pb,
                     int r, int c, int W, int s, int nS, int d) {
  int amin = max(0, (r - W + s) / s), amax = min(nS - 1, r / s);
  int bmin = max(0, (c - W + s) / s), bmax = min(nS - 1, c / s);
  float acc = 0.f;
  int cnt = 0;
  for (int a = amin; a <= amax; ++a)
    for (int b = bmin; b <= bmax; ++b) {
      const size_t i = (size_t)(a * nS + b) * D + d;
      acc += pa[i] + pb[i];
      ++cnt;
    }
  return acc / (float)cnt;
}

__global__ void k_combine(const float* __restrict__ p0, const float* __restrict__ p1,
                          const float* __restrict__ p2a, const float* __restrict__ p2b,
                          unsigned short* __restrict__ catb) {
  const int t = blockIdx.x, d = threadIdx.x;
  const int r = t >> 6, c = t & 63;
  unsigned short* o = catb + (size_t)t * 768;
  o[d]       = f2bf(gatherp(p0, r, c, 4, 2, 31, d));
  o[256 + d] = f2bf(gatherp(p1, r, c, 8, 4, 15, d));
  o[512 + d] = f2bf(gatherp2(p2a, p2b, r, c, 16, 8, 7, d));
}

// ---------------------------------------------------------------------------
// Block-wide sum of (a, b) over 256 threads
// ---------------------------------------------------------------------------
DEVFN float2 block_sum2(float a, float b) {
  __shared__ float sb[8];
#pragma unroll
  for (int m = 32; m; m >>= 1) { a += __shfl_xor(a, m); b += __shfl_xor(b, m); }
  const int w = threadIdx.x >> 6;
  __syncthreads();
  if ((threadIdx.x & 63) == 0) { sb[w] = a; sb[4 + w] = b; }
  __syncthreads();
  return make_float2(sb[0] + sb[1] + sb[2] + sb[3], sb[4] + sb[5] + sb[6] + sb[7]);
}

// out = LN(a (+ b)); optional bf16 dual write. In-place safe (out==a).
__global__ __launch_bounds__(256) void k_ln(float* __restrict__ out, unsigned short* __restrict__ outb,
                                            const float* __restrict__ a, const float* __restrict__ b,
                                            const float* __restrict__ g, const float* __restrict__ be) {
  const size_t i = (size_t)blockIdx.x * D + threadIdx.x;
  float v = a[i] + (b ? b[i] : 0.f);
  float2 s = block_sum2(v, v * v);
  float mean = s.x * (1.f / D);
  float var = s.y * (1.f / D) - mean * mean;
  const float r = (v - mean) * rsqrtf(var + 1e-5f) * g[threadIdx.x] + be[threadIdx.x];
  out[i] = r;
  if (outb) outb[i] = f2bf(r);
}

// xl = LN2(x + LN1(t1)); writes fp32 + bf16 (fuses the two post-fuse LNs)
__global__ __launch_bounds__(256) void k_ln_fuse(const float* __restrict__ t1,
                                                 const float* __restrict__ x,
                                                 float* __restrict__ xl,
                                                 unsigned short* __restrict__ xlb,
                                                 const float* __restrict__ fg,
                                                 const float* __restrict__ fbb,
                                                 const float* __restrict__ n1g,
                                                 const float* __restrict__ n1b) {
  const size_t i = (size_t)blockIdx.x * D + threadIdx.x;
  const float v1 = t1[i];
  float2 s1 = block_sum2(v1, v1 * v1);
  const float mean1 = s1.x * (1.f / D);
  const float var1 = s1.y * (1.f / D) - mean1 * mean1;
  const float r1 = (v1 - mean1) * rsqrtf(var1 + 1e-5f) * fg[threadIdx.x] + fbb[threadIdx.x];
  const float v2 = x[i] + r1;
  float2 s2 = block_sum2(v2, v2 * v2);
  const float mean2 = s2.x * (1.f / D);
  const float var2 = s2.y * (1.f / D) - mean2 * mean2;
  const float r2 = (v2 - mean2) * rsqrtf(var2 + 1e-5f) * n1g[threadIdx.x] + n1b[threadIdx.x];
  xl[i] = r2;
  xlb[i] = f2bf(r2);
}

// ---------------------------------------------------------------------------
// MFMA flash attention, split-KV x4: grid (S/64, NH, 4); 1024 keys/block in
// sixteen 64-key iterations. exp2-domain softmax; K LDS ping-pong [64][32];
// V subtiled + tr-reads; defer-max (check even iters); split-l chains.
// ---------------------------------------------------------------------------
__global__ __launch_bounds__(256) void k_flash_mfma(const unsigned short* __restrict__ Qg,
                                                    const unsigned short* __restrict__ Kg,
                                                    const unsigned short* __restrict__ Vg,
                                                    unsigned short* __restrict__ po,
                                                    float* __restrict__ pml) {
  const int h = blockIdx.y, z = blockIdx.z;
  const int tid = threadIdx.x;
  const int wave = tid >> 6, lane = tid & 63;
  const int lr = lane & 15, lg = lane >> 4;
  constexpr int NT2 = 16;            // 16 iters x 64 keys = 1024 keys per slice

  __shared__ unsigned short KS[2][64][32];
  __shared__ unsigned short VS[2][2048];

  const int q0 = blockIdx.x * 64 + wave * 16;
  const int kbase = z * 1024;

  const bf16x8 qfrag = *(const bf16x8*)(Qg + (size_t)(q0 + lr) * D + h * DH + lg * 8);

  f32x4 o0 = {0.f, 0.f, 0.f, 0.f}, o1 = {0.f, 0.f, 0.f, 0.f};
  float mrow = -INFINITY, lrow = 0.f;

  const unsigned vsbase0 =
      (unsigned)(unsigned long long)(const void*)&VS[0][0] + (unsigned)(lg * 128 + lr * 2);

  const int key = tid >> 2, c8 = (tid & 3) * 8;
  const int vidx = (c8 >> 4) * 1024 + (key >> 2) * 64 + (key & 3) * 16 + (c8 & 15);
  const unsigned short* kp = Kg + (size_t)(kbase + key) * D + h * DH + c8;
  const unsigned short* vp = Vg + (size_t)(kbase + key) * D + h * DH + c8;
  constexpr int KSTEP = 64 * D;

  // prologue: stage tile 0 into buf 0
  {
    bf16x8 k0r = *(const bf16x8*)kp;
    bf16x8 v0r = *(const bf16x8*)vp;
    *(bf16x8*)&KS[0][key][c8] = k0r;
    *(bf16x8*)&VS[0][vidx] = v0r;
  }
  __syncthreads();

  for (int kt = 0; kt < NT2; ++kt) {
    const int cur = kt & 1;
    const int ktn = (kt + 1 < NT2) ? kt + 1 : kt;
    bf16x8 kreg = *(const bf16x8*)(kp + (size_t)ktn * KSTEP);
    bf16x8 vreg = *(const bf16x8*)(vp + (size_t)ktn * KSTEP);

    // swapped QK^T: s[k16][r] = S[q=lr][key = k16*16 + lg*4 + r] (log2 units)
    f32x4 s[4];
    __builtin_amdgcn_s_setprio(1);
#pragma unroll
    for (int k16 = 0; k16 < 4; ++k16) {
      bf16x8 ka = *(const bf16x8*)&KS[cur][k16 * 16 + lr][lg * 8];
      f32x4 zc = {0.f, 0.f, 0.f, 0.f};
      s[k16] = __builtin_amdgcn_mfma_f32_16x16x32_bf16(ka, qfrag, zc, 0, 0, 0);
    }
    __builtin_amdgcn_s_setprio(0);

    // issue V tr-reads early
    const unsigned vb = vsbase0 + (unsigned)(cur << 12);
    u32x2 tv000, tv001, tv010, tv011, tv100, tv101, tv110, tv111;
    asm volatile("ds_read_b64_tr_b16 %0, %1 offset:0"    : "=v"(tv000) : "v"(vb));
    asm volatile("ds_read_b64_tr_b16 %0, %1 offset:2048" : "=v"(tv001) : "v"(vb));
    asm volatile("ds_read_b64_tr_b16 %0, %1 offset:512"  : "=v"(tv010) : "v"(vb));
    asm volatile("ds_read_b64_tr_b16 %0, %1 offset:2560" : "=v"(tv011) : "v"(vb));
    asm volatile("ds_read_b64_tr_b16 %0, %1 offset:1024" : "=v"(tv100) : "v"(vb));
    asm volatile("ds_read_b64_tr_b16 %0, %1 offset:3072" : "=v"(tv101) : "v"(vb));
    asm volatile("ds_read_b64_tr_b16 %0, %1 offset:1536" : "=v"(tv110) : "v"(vb));
    asm volatile("ds_read_b64_tr_b16 %0, %1 offset:3584" : "=v"(tv111) : "v"(vb));

    // exp2-domain online softmax; defer-max checked every 2nd iter
    // (P bounded by 2^(growth+11) between checks — bf16/fp32 safe)
    if ((kt & 1) == 0) {
      float tm = fmaxf(fmaxf(fmaxf(s[0][0], s[0][1]), fmaxf(s[0][2], s[0][3])),
                       fmaxf(fmaxf(s[1][0], s[1][1]), fmaxf(s[1][2], s[1][3])));
      tm = fmaxf(tm, fmaxf(fmaxf(fmaxf(s[2][0], s[2][1]), fmaxf(s[2][2], s[2][3])),
                           fmaxf(fmaxf(s[3][0], s[3][1]), fmaxf(s[3][2], s[3][3]))));
      const bool skip = __all(tm - mrow <= 11.f);
      if (!skip) {
        float tmm = fmaxf(tm, __shfl_xor(tm, 16));
        tmm = fmaxf(tmm, __shfl_xor(tmm, 32));
        const float nm = fmaxf(mrow, tmm);
        const float cfac = ex2(mrow - nm);
        mrow = nm;
        lrow *= cfac;
#pragma unroll
        for (int r = 0; r < 4; ++r) {
          const float cr = __shfl(cfac, lg * 4 + r);
          o0[r] *= cr; o1[r] *= cr;
        }
      }
    }
    // 4 independent accumulation chains
    float pa = 0.f, pb = 0.f, pc = 0.f, pd = 0.f;
#pragma unroll
    for (int k16 = 0; k16 < 4; ++k16) {
      s[k16][0] = ex2(s[k16][0] - mrow); pa += s[k16][0];
      s[k16][1] = ex2(s[k16][1] - mrow); pb += s[k16][1];
      s[k16][2] = ex2(s[k16][2] - mrow); pc += s[k16][2];
      s[k16][3] = ex2(s[k16][3] - mrow); pd += s[k16][3];
    }
    lrow += (pa + pb) + (pc + pd);

    asm volatile("s_waitcnt lgkmcnt(0)" ::: "memory");
    __builtin_amdgcn_sched_barrier(0);

    // PV: a = lane-local P (packed via cvt_pk), b = tr-read V fragments
    union VB { u32x2 u2[2]; bf16x8 b; };
    __builtin_amdgcn_s_setprio(1);
#pragma unroll
    for (int kt2 = 0; kt2 < 2; ++kt2) {
      union { unsigned w[4]; bf16x8 v; } pu;
      pu.w[0] = pk2(s[2 * kt2][0], s[2 * kt2][1]);
      pu.w[1] = pk2(s[2 * kt2][2], s[2 * kt2][3]);
      pu.w[2] = pk2(s[2 * kt2 + 1][0], s[2 * kt2 + 1][1]);
      pu.w[3] = pk2(s[2 * kt2 + 1][2], s[2 * kt2 + 1][3]);
      VB v0f, v1f;
      if (kt2 == 0) { v0f.u2[0] = tv000; v0f.u2[1] = tv010; v1f.u2[0] = tv001; v1f.u2[1] = tv011; }
      else          { v0f.u2[0] = tv100; v0f.u2[1] = tv110; v1f.u2[0] = tv101; v1f.u2[1] = tv111; }
      o0 = __builtin_amdgcn_mfma_f32_16x16x32_bf16(pu.v, v0f.b, o0, 0, 0, 0);
      o1 = __builtin_amdgcn_mfma_f32_16x16x32_bf16(pu.v, v1f.b, o1, 0, 0, 0);
    }
    __builtin_amdgcn_s_setprio(0);

    if (kt + 1 < NT2) {
      *(bf16x8*)&KS[cur ^ 1][key][c8] = kreg;
      *(bf16x8*)&VS[cur ^ 1][vidx] = vreg;
      __syncthreads();
    }
  }

  // single cross-lane l reduction (deferred from the loop)
  lrow += __shfl_xor(lrow, 16);
  lrow += __shfl_xor(lrow, 32);

  // partial outputs (unnormalized, bf16) + per-q (m [log2], l)
#pragma unroll
  for (int r = 0; r < 4; ++r) {
    unsigned short* op = po + (size_t)z * S * D + (size_t)(q0 + lg * 4 + r) * D + h * DH + lr;
    op[0]  = f2bf(o0[r]);
    op[16] = f2bf(o1[r]);
  }
  if (lane < 16) {
    float* mlp = pml + ((size_t)(z * NH + h) * S + q0 + lr) * 2;
    mlp[0] = mrow;
    mlp[1] = lrow;
  }
}

// merge the 4 KV slices: out bf16 t1b[q][d] (m in log2 domain)
__global__ __launch_bounds__(256) void k_fmerge(const unsigned short* __restrict__ po,
                                                const float* __restrict__ pml,
                                                unsigned short* __restrict__ t1b) {
  const int t = blockIdx.x, d = threadIdx.x;
  const int h = d >> 5;
  float m[NSPLIT], l[NSPLIT];
  float M = -INFINITY;
#pragma unroll
  for (int z = 0; z < NSPLIT; ++z) {
    const float* ml = pml + ((size_t)(z * NH + h) * S + t) * 2;
    m[z] = ml[0]; l[z] = ml[1];
    M = fmaxf(M, m[z]);
  }
  float L = 0.f, acc = 0.f;
#pragma unroll
  for (int z = 0; z < NSPLIT; ++z) {
    const float a = ex2(m[z] - M);
    L += l[z] * a;
    acc += bf2f(po[(size_t)z * S * D + (size_t)t * D + d]) * a;
  }
  t1b[(size_t)t * D + d] = f2bf(acc / L);
}

// ---------------------------------------------------------------------------
// Gate helpers (gate matvec+softmax fused into k_xf)
// ---------------------------------------------------------------------------
__global__ __launch_bounds__(256) void k_colmean(const float* __restrict__ xl,
                                                 const float* __restrict__ xg,
                                                 float* __restrict__ gbuf) {
  const int j = threadIdx.x;
  const int t0 = blockIdx.x * 16;
  float s = 0.f;
  for (int t = 0; t < 16; ++t) {
    size_t i = (size_t)(t0 + t) * D + j;
    s += xl[i] + xg[i];
  }
  atomicAdd(&gbuf[j], s * 0.5f);
}

__global__ __launch_bounds__(256) void k_xf(const float* __restrict__ xl,
                                            const float* __restrict__ xg,
                                            const float* __restrict__ gbuf,
                                            const float* __restrict__ gw,
                                            const float* __restrict__ gb,
                                            float* __restrict__ xf,
                                            unsigned short* __restrict__ xfb) {
  __shared__ float ab[2];
  {
    const int j = threadIdx.x;
    const float gm = gbuf[j] * (1.f / (float)S);
    float2 s = block_sum2(gm * gw[2 * j], gm * gw[2 * j + 1]);
    if (j == 0) {
      const float g0 = s.x + gb[0], g1 = s.y + gb[1];
      const float mx = fmaxf(g0, g1);
      const float e0 = __expf(g0 - mx), e1 = __expf(g1 - mx);
      ab[0] = e0 / (e0 + e1);
      ab[1] = e1 / (e0 + e1);
    }
    __syncthreads();
  }
  const float alpha = ab[0], beta = ab[1];
  const size_t i = ((size_t)blockIdx.x * 256 + threadIdx.x) * 4;
  float4 a = *(const float4*)(xg + i);
  float4 b = *(const float4*)(xl + i);
  float4 r;
  r.x = alpha * a.x + beta * b.x;
  r.y = alpha * a.y + beta * b.y;
  r.z = alpha * a.z + beta * b.z;
  r.w = alpha * a.w + beta * b.w;
  *(float4*)(xf + i) = r;
  *(uint2*)(xfb + i) = make_uint2(pk2(r.x, r.y), pk2(r.z, r.w));
}

// ===========================================================================
extern "C" void kernel_launch(void* const* d_in, const int* in_sizes, int n_in,
                              void* d_out, int out_size, void* d_ws, size_t ws_size,
                              hipStream_t stream) {
  const float* x   = (const float*)d_in[0];
  const float* fw  = (const float*)d_in[2];
  const float* fb  = (const float*)d_in[3];
  const float* fg  = (const float*)d_in[4];
  const float* fbb = (const float*)d_in[5];
  const float* wq  = (const float*)d_in[6];
  const float* wk  = (const float*)d_in[7];
  const float* wv  = (const float*)d_in[8];
  const float* bq  = (const float*)d_in[9];
  const float* bk  = (const float*)d_in[10];
  const float* bv  = (const float*)d_in[11];
  const float* wo  = (const float*)d_in[12];
  const float* bo  = (const float*)d_in[13];
  const float* gw  = (const float*)d_in[14];
  const float* gb  = (const float*)d_in[15];
  const float* w1  = (const float*)d_in[16];
  const float* b1  = (const float*)d_in[17];
  const float* w2  = (const float*)d_in[18];
  const float* b2  = (const float*)d_in[19];
  const float* n1g = (const float*)d_in[20];
  const float* n1b = (const float*)d_in[21];
  const float* n2g = (const float*)d_in[22];
  const float* n2b = (const float*)d_in[23];
  const float* n3g = (const float*)d_in[24];
  const float* n3b = (const float*)d_in[25];
  float* out = (float*)d_out;

  // ---- workspace carve (bytes) ----
  char* base = (char*)d_ws;
  size_t off = 0;
  auto carve = [&](size_t bytes) { char* p = base + off; off += (bytes + 255) & ~(size_t)255; return p; };
  float* p0  = (float*)carve(961 * 256 * 4);
  float* p1  = (float*)carve(225 * 256 * 4);
  float* p2a = (float*)carve(49 * 256 * 4);
  float* p2b = (float*)carve(49 * 256 * 4);
  unsigned short* fwT = (unsigned short*)carve(256 * 768 * 2);
  unsigned short* wqkvT = (unsigned short*)carve(3 * 256 * 256 * 2);  // q|k|v
  unsigned short* wqT = wqkvT;
  unsigned short* wkT = wqkvT + 256 * 256;
  unsigned short* wvT = wqkvT + 2 * 256 * 256;
  unsigned short* woT = (unsigned short*)carve(256 * 256 * 2);
  unsigned short* w1T = (unsigned short*)carve(1024 * 256 * 2);
  unsigned short* w2T = (unsigned short*)carve(256 * 1024 * 2);
  char* R = carve(8388608);   // catb(6.3MB) -> xg(4MB) -> hbuf(8MB)
  unsigned short* catb = (unsigned short*)R;
  float* xg            = (float*)R;
  unsigned short* hbuf = (unsigned short*)R;
  unsigned short* po = (unsigned short*)carve((size_t)NSPLIT * S * D * 2);  // 8MB
  float* pml = (float*)carve((size_t)NSPLIT * NH * S * 2 * 4);
  unsigned short* qb = (unsigned short*)carve((size_t)S * D * 2);
  unsigned short* kb = (unsigned short*)carve((size_t)S * D * 2);
  unsigned short* vb = (unsigned short*)carve((size_t)S * D * 2);
  float* xf            = (float*)qb;             // qb+kb region, dead after flash
  unsigned short* xfb  = vb;                     // vb region, dead after flash
  float* t1  = (float*)carve((size_t)S * D * 4); // fuse out; later ffo
  float* ffo = t1;
  unsigned short* t1b = (unsigned short*)carve((size_t)S * D * 2);
  float* xl  = (float*)carve((size_t)S * D * 4);
  unsigned short* xlb = (unsigned short*)carve((size_t)S * D * 2);
  float* gbuf = (float*)carve(264 * 4);

  hipMemsetAsync(gbuf, 0, 264 * sizeof(float), stream);

  // weight pre-transpose (bf16 WT[N][K]; wq/wk/wv contiguous)
  k_wt<<<dim3(960), dim3(256), 0, stream>>>(fw, wq, wk, wv, wo, w1, w2,
                                            fwT, wqT, wkT, wvT, woT, w1T, w2T);
  // local multi-scale window attention (single merged dispatch; p2 dual-buf)
  k_local_all<<<dim3(NB4 + NB8 + NB16), dim3(256), 0, stream>>>(x, p0, p1, p2a, p2b);
  // scatter/avg -> catb[S][768] bf16
  k_combine<<<dim3(S), dim3(256), 0, stream>>>(p0, p1, p2a, p2b, catb);
  // fuse GEMM + fused LN pair
  k_gemm_m<768, 0, 0><<<dim3(S / 64, 4), dim3(64), 0, stream>>>(catb, fwT, fb, t1, 256);
  k_ln_fuse<<<dim3(S), dim3(256), 0, stream>>>(t1, x, xl, xlb, fg, fbb, n1g, n1b);
  // global MHA (bf16 q/k/v; single QKV dispatch; q pre-scaled w/ log2e)
  k_gemm_qkv<<<dim3(S / 64, 12), dim3(64), 0, stream>>>(xlb, wqkvT, bq, bk, bv, qb, kb, vb);
  k_flash_mfma<<<dim3(S / 64, NH, NSPLIT), dim3(256), 0, stream>>>(qb, kb, vb, po, pml);
  k_fmerge<<<dim3(S), dim3(256), 0, stream>>>(po, pml, t1b);
  k_gemm_m<256, 0, 0><<<dim3(S / 64, 4), dim3(64), 0, stream>>>(t1b, woT, bo, xf, 256);
  k_ln<<<dim3(S), dim3(256), 0, stream>>>(xg, nullptr, xl, xf, n2g, n2b);
  // gate (mean via atomics; matvec+softmax fused into k_xf)
  k_colmean<<<dim3(256), dim3(256), 0, stream>>>(xl, xg, gbuf);
  k_xf<<<dim3(S * D / 1024), dim3(256), 0, stream>>>(xl, xg, gbuf, gw, gb, xf, xfb);
  // FFN + final LN
  k_gemm_m<256, 1, 1><<<dim3(S / 64, 16), dim3(64), 0, stream>>>(xfb, w1T, b1, hbuf, 1024);
  k_gemm_m<1024, 0, 0><<<dim3(S / 64, 4), dim3(64), 0, stream>>>(hbuf, w2T, b2, ffo, 256);
  k_ln<<<dim3(S), dim3(256), 0, stream>>>(out, nullptr, xf, ffo, n3g, n3b);
}